// Round 9
// baseline (863.314 us; speedup 1.0000x reference)
//
#include <hip/hip_runtime.h>
#include <stdint.h>

#define TOKENS 4096
#define HIDDEN 2048
#define INTER  1408
#define NEXP   16
#define TOPK   6
#define NPAIR  (TOKENS*TOPK)          // 24576
#define BM     128
#define MAXTILES (NPAIR/BM + NEXP)    // 208 (128-row tiles, fallback path)
#define MAXT2  (NPAIR/256 + NEXP)     // 112 (256-row tiles, main path)
#define NT1    (INTER/128)            // 11
#define NT2    (HIDDEN/128)           // 16 (fallback)
#define NT2W   (HIDDEN/256)           // 8  (wide g2)

typedef __attribute__((ext_vector_type(8)))  short bf16x8;
typedef __attribute__((ext_vector_type(4)))  float f32x4;
typedef __attribute__((ext_vector_type(16))) float f32x16;

__device__ __forceinline__ short f2bf(float f){
  union { float f; uint32_t u; } v; v.f = f;
  uint32_t r = (v.u + 0x7FFFu + ((v.u >> 16) & 1u)) >> 16;
  return (short)(r & 0xFFFFu);
}

__device__ __forceinline__ void gld16(const void* g, const void* l){
  __builtin_amdgcn_global_load_lds((const __attribute__((address_space(1))) void*)g,
                                   (__attribute__((address_space(3))) void*)l, 16, 0, 0);
}

__device__ __forceinline__ f32x4 ntld4(const float* p){
  return __builtin_nontemporal_load((const f32x4*)p);
}

#define SB() __builtin_amdgcn_sched_barrier(0)
#define BAR() __builtin_amdgcn_s_barrier()
#define WAITV(n) asm volatile("s_waitcnt vmcnt(" #n ")" ::: "memory")
#define WAITL() asm volatile("s_waitcnt lgkmcnt(0)" ::: "memory")

// ---------------- setup kernels ----------------

__global__ void k_xcast(const float* __restrict__ x, short* __restrict__ xb){
  int i = (blockIdx.x * 256 + threadIdx.x) * 8;
  f32x4 a = ntld4(x + i);
  f32x4 b = ntld4(x + i + 4);
  bf16x8 o;
  #pragma unroll
  for (int j = 0; j < 4; ++j){ o[j] = f2bf(a[j]); o[4+j] = f2bf(b[j]); }
  *(bf16x8*)(xb + i) = o;
}

// merged w0+w1 dequant: one row per block
__global__ void k_deq01(const float* __restrict__ w0, const float* __restrict__ s0,
                        const float* __restrict__ w1, const float* __restrict__ s1,
                        short* __restrict__ o0, short* __restrict__ o1){
  int row = blockIdx.x;
  const float* w; const float* s; short* o;
  if (row < NEXP * INTER){ w = w0; s = s0; o = o0; }
  else { row -= NEXP * INTER; w = w1; s = s1; o = o1; }
  const size_t base = (size_t)row * HIDDEN;
  const int c = threadIdx.x * 8;
  float sc = s[(size_t)row * (HIDDEN/128) + (c >> 7)];
  f32x4 a = ntld4(w + base + c);
  f32x4 b = ntld4(w + base + c + 4);
  bf16x8 h;
  #pragma unroll
  for (int j = 0; j < 4; ++j){ h[j] = f2bf(a[j] * sc); h[4+j] = f2bf(b[j] * sc); }
  *(bf16x8*)(o + base + c) = h;
}

// legacy per-tensor dequant (fallback path)
__global__ void k_dequant(const float* __restrict__ w, const float* __restrict__ s,
                          short* __restrict__ o, int rowlen, int nblk){
  const int row = blockIdx.x;
  const size_t base = (size_t)row * rowlen;
  for (int c = threadIdx.x * 8; c < rowlen; c += blockDim.x * 8){
    float sc = s[(size_t)row * nblk + (c >> 7)];
    f32x4 a = *(const f32x4*)(w + base + c);
    f32x4 b = *(const f32x4*)(w + base + c + 4);
    bf16x8 h;
    #pragma unroll
    for (int j = 0; j < 4; ++j){ h[j] = f2bf(a[j] * sc); h[4+j] = f2bf(b[j] * sc); }
    *(bf16x8*)(o + base + c) = h;
  }
}

__global__ void k_count(const int* __restrict__ sel, int* __restrict__ cnt){
  int p = blockIdx.x * 256 + threadIdx.x;
  if (p < NPAIR) atomicAdd(&cnt[sel[p]], 1);
}

__global__ void k_scan(const int* __restrict__ cnt, int* __restrict__ offsets,
                       int2* __restrict__ tiles, int* __restrict__ ntiles,
                       int2* __restrict__ tiles2, int* __restrict__ ntiles2){
  if (threadIdx.x != 0) return;
  int off = 0, nt = 0, nt2 = 0;
  for (int e = 0; e < NEXP; ++e){
    offsets[e] = off;
    int c = cnt[e];
    for (int m = 0; m < c; m += BM){
      int rows = c - m; if (rows > BM) rows = BM;
      tiles[nt++] = make_int2(off + m, (e << 16) | rows);
    }
    for (int m = 0; m < c; m += 256){
      int rows = c - m; if (rows > 256) rows = 256;
      tiles2[nt2++] = make_int2(off + m, (e << 16) | rows);
    }
    off += c;
  }
  offsets[NEXP] = off;
  *ntiles = nt;
  *ntiles2 = nt2;
}

__global__ void k_scatter(const int* __restrict__ sel, const int* __restrict__ offsets,
                          int* __restrict__ cursor, int* __restrict__ pair_tk){
  int p = blockIdx.x * 256 + threadIdx.x;
  if (p >= NPAIR) return;
  int e = sel[p];
  int pos = offsets[e] + atomicAdd(&cursor[e], 1);
  pair_tk[pos] = (p / TOPK) * 8 + (p % TOPK);   // t<<3 | slot
}

// ======== main path: 256-row tiles, BK=64, 512 thr, K-half-region pipeline,
// ======== mfma_f32_32x32x16_bf16 (matrix ceiling 2382 vs 2075 TF; same LDS traffic)
// LDS layout [buf*2+kh][rows*32 shorts]; region contiguous -> global_load_lds
// linear. Granule XOR swizzle (both sides): LDS pos p in row r holds global
// granule p ^ ((r>>1)&3); verified conflict-free (r7: SQ_LDS_BANK_CONFLICT=0).
// Fragments (32x32x16): A/B lane l -> row/col = l&31, k = (l>>5)*8+j;
// C/D col = lane&31, row = (reg&3)+8*(reg>>2)+4*(lane>>5).
// Schedule: phase (t,0) stages (t+1,kh1), phase (t,1) stages (t+2,kh0);
// region consumed 3 phases after issue; counted vmcnt (never 0 mid-loop).

__global__ __launch_bounds__(512) void k_g1(
    const short* __restrict__ xb,
    const short* __restrict__ w0b, const short* __restrict__ w1b,
    const int2* __restrict__ tiles2, const int* __restrict__ ntiles2,
    const int* __restrict__ pair_tk, short* __restrict__ act,
    const float* __restrict__ w2, const float* __restrict__ s2,
    short* __restrict__ w2b)
{
  const int nwg = MAXT2 * NT1;                 // 1232, %8==0
  const int orig = (int)(blockIdx.y * MAXT2 + blockIdx.x);
  const int wg = (orig & 7) * (nwg >> 3) + (orig >> 3);
  const int tx = wg % MAXT2, ty = wg / MAXT2;
  const int tid = threadIdx.x, w = tid >> 6, lane = tid & 63;

  __shared__ short lA[4][8192];   // [buf*2+kh][256 rows * 32 shorts] = 16KB each
  __shared__ short lB[4][8192];

  if (tx < *ntiles2){
    const int2 td = tiles2[tx];
    const int mstart = td.x;
    const int e  = td.y >> 16;
    const int vr = td.y & 0xFFFF;

    // staging: region granule s = (w*2+i)*64+lane; row r = s>>2;
    // swizzled source granule j = (s&3)^((s>>3)&3).
    // B interleave (32-row granules): even G -> w0 rows (G>>1)*32.., odd -> w1.
    const short* pA[2]; const short* pB[2]; int sg8[2];
    #pragma unroll
    for (int i = 0; i < 2; ++i){
      int s = (w * 2 + i) * 64 + lane;
      int r = s >> 2, j = (s & 3) ^ ((s >> 3) & 3);
      sg8[i] = s * 8;
      int p = mstart + r; if (p >= NPAIR) p = NPAIR - 1;
      pA[i] = xb + (size_t)(pair_tk[p] >> 3) * HIDDEN + j * 8;
      int G = r >> 5, srow = (G >> 1) * 32 + (r & 31);
      const short* wsrc = (G & 1) ? w1b : w0b;
      pB[i] = wsrc + ((size_t)e * INTER + (size_t)ty * 128 + srow) * HIDDEN + j * 8;
    }
    auto stage = [&](int slot, int ko){     // ko = tile*64 + kh*32 (shorts)
      #pragma unroll
      for (int i = 0; i < 2; ++i) gld16(pA[i] + ko, &lA[slot][sg8[i]]);
      #pragma unroll
      for (int i = 0; i < 2; ++i) gld16(pB[i] + ko, &lB[slot][sg8[i]]);
    };

    f32x16 acc[2][4];
    #pragma unroll
    for (int i = 0; i < 2; ++i)
      #pragma unroll
      for (int j = 0; j < 4; ++j) acc[i][j] = (f32x16)0.f;

    const int c32 = lane & 31, kg = lane >> 5;
    const int wm = w >> 1, wn = w & 1;
    int arow[2], axor[2], brow[4], bxor[4];
    #pragma unroll
    for (int mf = 0; mf < 2; ++mf){
      int r = wm * 64 + mf * 32 + c32;
      arow[mf] = r * 32; axor[mf] = (r >> 1) & 3;
    }
    #pragma unroll
    for (int nf = 0; nf < 4; ++nf){
      int r = wn * 128 + nf * 32 + c32;
      brow[nf] = r * 32; bxor[nf] = (r >> 1) & 3;
    }

    stage(0, 0); stage(1, 32); stage(2, 64); stage(3, 96);

    #pragma unroll 1
    for (int t = 0; t < 32; ++t){
      const int b = t & 1;
      #pragma unroll
      for (int h = 0; h < 2; ++h){
        // counted vmcnt: steady-state 12 outstanding, free next region (4 loads)
        if (t == 0 && h == 0)      { WAITV(12); }
        else if (t < 31)           { WAITV(8);  }
        else if (h == 0)           { WAITV(4);  }
        else                       { WAITV(0);  }
        SB(); BAR(); SB();
        const short* A = lA[b*2 + h];
        const short* B = lB[b*2 + h];
        bf16x8 av[2][2], bv[4][2];
        #pragma unroll
        for (int mf = 0; mf < 2; ++mf)
          #pragma unroll
          for (int k2 = 0; k2 < 2; ++k2)
            av[mf][k2] = *(const bf16x8*)&A[arow[mf] + (((k2*2+kg) ^ axor[mf]) * 8)];
        #pragma unroll
        for (int nf = 0; nf < 4; ++nf)
          #pragma unroll
          for (int k2 = 0; k2 < 2; ++k2)
            bv[nf][k2] = *(const bf16x8*)&B[brow[nf] + (((k2*2+kg) ^ bxor[nf]) * 8)];
        // stage next region into the just-freed slot
        if (h == 0){ if (t >= 1 && t + 1 < 32) stage(((t+1)&1)*2 + 1, (t+1)*64 + 32); }
        else       { if (t + 2 < 32)           stage(b*2, (t+2)*64); }
        WAITL(); SB();
        __builtin_amdgcn_s_setprio(1);
        #pragma unroll
        for (int k2 = 0; k2 < 2; ++k2)
          #pragma unroll
          for (int nf = 0; nf < 4; ++nf)
            #pragma unroll
            for (int mf = 0; mf < 2; ++mf)
              acc[mf][nf] = __builtin_amdgcn_mfma_f32_32x32x16_bf16(av[mf][k2], bv[nf][k2], acc[mf][nf], 0, 0, 0);
        __builtin_amdgcn_s_setprio(0);
        SB(); BAR(); SB();
      }
    }

    // epilogue: gate=acc[mf][2t2], up=acc[mf][2t2+1] -> act col ty*128+(wn*2+t2)*32+c32
    #pragma unroll
    for (int mf = 0; mf < 2; ++mf){
      #pragma unroll
      for (int r = 0; r < 16; ++r){
        int row = wm * 64 + mf * 32 + (r & 3) + 8 * (r >> 2) + 4 * kg;
        if (row < vr){
          short* ar = act + (size_t)(mstart + row) * INTER + (size_t)ty * 128 + c32;
          #pragma unroll
          for (int t2 = 0; t2 < 2; ++t2){
            float g = acc[mf][2*t2][r], u = acc[mf][2*t2+1][r];
            float a = g / (1.f + __expf(-g)) * u;
            ar[(wn * 2 + t2) * 32] = f2bf(a);
          }
        }
      }
    }
  }

  // ---- w2 dequant tail (all blocks; fills g1 tail imbalance; g2 runs after) ----
  {
    const int total = NEXP * HIDDEN * (INTER / 8);   // 5,767,168 granules
    for (int gi = orig * 512 + tid; gi < total; gi += nwg * 512){
      int row = gi / (INTER / 8);
      int c = (gi - row * (INTER / 8)) * 8;
      const size_t base = (size_t)row * INTER;
      float sc = s2[(size_t)row * 11 + (c >> 7)];
      f32x4 a = ntld4(w2 + base + c);
      f32x4 b = ntld4(w2 + base + c + 4);
      bf16x8 h;
      #pragma unroll
      for (int j = 0; j < 4; ++j){ h[j] = f2bf(a[j] * sc); h[4+j] = f2bf(b[j] * sc); }
      *(bf16x8*)(w2b + base + c) = h;
    }
  }
}

// gemm2 WIDE: BN=256, 32x32x16 MFMA, same pipeline
__global__ __launch_bounds__(512) void k_g2(
    const short* __restrict__ act, const short* __restrict__ w2b,
    const int2* __restrict__ tiles2, const int* __restrict__ ntiles2,
    const int* __restrict__ pair_tk, float* __restrict__ out)
{
  const int nwg = MAXT2 * NT2W;                // 896, %8==0
  const int orig = (int)(blockIdx.y * MAXT2 + blockIdx.x);
  const int wg = (orig & 7) * (nwg >> 3) + (orig >> 3);
  const int tx = wg % MAXT2, ty = wg / MAXT2;
  if (tx >= *ntiles2) return;
  const int2 td = tiles2[tx];
  const int mstart = td.x;
  const int e  = td.y >> 16;
  const int vr = td.y & 0xFFFF;

  __shared__ short lA[4][8192];
  __shared__ short lB[4][8192];

  const int tid = threadIdx.x, w = tid >> 6, lane = tid & 63;

  const short* pA[2]; const short* pB[2]; int sg8[2];
  #pragma unroll
  for (int i = 0; i < 2; ++i){
    int s = (w * 2 + i) * 64 + lane;
    int r = s >> 2, j = (s & 3) ^ ((s >> 3) & 3);
    sg8[i] = s * 8;
    int p = mstart + r; if (p >= NPAIR) p = NPAIR - 1;
    pA[i] = act + (size_t)p * INTER + j * 8;
    pB[i] = w2b + ((size_t)e * HIDDEN + (size_t)ty * 256 + r) * INTER + j * 8;
  }
  auto stage = [&](int slot, int ko){
    #pragma unroll
    for (int i = 0; i < 2; ++i) gld16(pA[i] + ko, &lA[slot][sg8[i]]);
    #pragma unroll
    for (int i = 0; i < 2; ++i) gld16(pB[i] + ko, &lB[slot][sg8[i]]);
  };

  f32x16 acc[2][4];
  #pragma unroll
  for (int i = 0; i < 2; ++i)
    #pragma unroll
    for (int j = 0; j < 4; ++j) acc[i][j] = (f32x16)0.f;

  const int c32 = lane & 31, kg = lane >> 5;
  const int wm = w >> 1, wn = w & 1;
  int arow[2], axor[2], brow[4], bxor[4];
  #pragma unroll
  for (int mf = 0; mf < 2; ++mf){
    int r = wm * 64 + mf * 32 + c32;
    arow[mf] = r * 32; axor[mf] = (r >> 1) & 3;
  }
  #pragma unroll
  for (int nf = 0; nf < 4; ++nf){
    int r = wn * 128 + nf * 32 + c32;
    brow[nf] = r * 32; bxor[nf] = (r >> 1) & 3;
  }

  stage(0, 0); stage(1, 32); stage(2, 64); stage(3, 96);

  #pragma unroll 1
  for (int t = 0; t < 22; ++t){
    const int b = t & 1;
    #pragma unroll
    for (int h = 0; h < 2; ++h){
      if (t == 0 && h == 0)      { WAITV(12); }
      else if (t < 21)           { WAITV(8);  }
      else if (h == 0)           { WAITV(4);  }
      else                       { WAITV(0);  }
      SB(); BAR(); SB();
      const short* A = lA[b*2 + h];
      const short* B = lB[b*2 + h];
      bf16x8 av[2][2], bv[4][2];
      #pragma unroll
      for (int mf = 0; mf < 2; ++mf)
        #pragma unroll
        for (int k2 = 0; k2 < 2; ++k2)
          av[mf][k2] = *(const bf16x8*)&A[arow[mf] + (((k2*2+kg) ^ axor[mf]) * 8)];
      #pragma unroll
      for (int nf = 0; nf < 4; ++nf)
        #pragma unroll
        for (int k2 = 0; k2 < 2; ++k2)
          bv[nf][k2] = *(const bf16x8*)&B[brow[nf] + (((k2*2+kg) ^ bxor[nf]) * 8)];
      if (h == 0){ if (t >= 1 && t + 1 < 22) stage(((t+1)&1)*2 + 1, (t+1)*64 + 32); }
      else       { if (t + 2 < 22)           stage(b*2, (t+2)*64); }
      WAITL(); SB();
      __builtin_amdgcn_s_setprio(1);
      #pragma unroll
      for (int k2 = 0; k2 < 2; ++k2)
        #pragma unroll
        for (int nf = 0; nf < 4; ++nf)
          #pragma unroll
          for (int mf = 0; mf < 2; ++mf)
            acc[mf][nf] = __builtin_amdgcn_mfma_f32_32x32x16_bf16(av[mf][k2], bv[nf][k2], acc[mf][nf], 0, 0, 0);
      __builtin_amdgcn_s_setprio(0);
      SB(); BAR(); SB();
    }
  }

  #pragma unroll
  for (int mf = 0; mf < 2; ++mf){
    #pragma unroll
    for (int r = 0; r < 16; ++r){
      int row = wm * 64 + mf * 32 + (r & 3) + 8 * (r >> 2) + 4 * kg;
      if (row < vr){
        int ptk = pair_tk[mstart + row];
        float* orow = out + ((size_t)(ptk >> 3) * TOPK + (ptk & 7)) * HIDDEN
                      + (size_t)ty * 256 + wn * 128 + c32;
        #pragma unroll
        for (int nf = 0; nf < 4; ++nf)
          orow[nf * 32] = acc[mf][nf][r];
      }
    }
  }
}

// ======== fallback GEMMs (in-GEMM dequant, round-1 proven) ========

__global__ __launch_bounds__(256) void k_gemm1(
    const short* __restrict__ xb,
    const float* __restrict__ w0, const float* __restrict__ s0,
    const float* __restrict__ w1, const float* __restrict__ s1,
    const int2* __restrict__ tiles, const int* __restrict__ ntiles,
    const int* __restrict__ pair_tk, short* __restrict__ act)
{
  if ((int)blockIdx.x >= *ntiles) return;
  const int2 td = tiles[blockIdx.x];
  const int mstart = td.x;
  const int e  = td.y >> 16;
  const int vr = td.y & 0xFFFF;
  const int tid = threadIdx.x;
  const int lane = tid & 63;

  __shared__ short lA[BM * 32];
  __shared__ short lB0[BM * 40];
  __shared__ short lB1[BM * 40];

  const int r0 = tid >> 2, r1 = 64 + (tid >> 2);
  const int seg = tid & 3;
  int p0 = mstart + r0; if (p0 >= NPAIR) p0 = NPAIR - 1;
  int p1 = mstart + r1; if (p1 >= NPAIR) p1 = NPAIR - 1;
  const short* arow0 = xb + (size_t)(pair_tk[p0] >> 3) * HIDDEN + (seg ^ ((r0 >> 1) & 3)) * 8;
  const short* arow1 = xb + (size_t)(pair_tk[p1] >> 3) * HIDDEN + (seg ^ ((r1 >> 1) & 3)) * 8;
  const short* ldsA0 = &lA[tid * 8];
  const short* ldsA1 = &lA[2048 + tid * 8];

  const int brow = tid >> 1, half = tid & 1;
  const int gbrow = blockIdx.y * BM + brow;
  const float* w0row = w0 + ((size_t)e * INTER + gbrow) * HIDDEN + half * 16;
  const float* w1row = w1 + ((size_t)e * INTER + gbrow) * HIDDEN + half * 16;
  const float* s0row = s0 + ((size_t)e * INTER + gbrow) * (HIDDEN / 128);
  const float* s1row = s1 + ((size_t)e * INTER + gbrow) * (HIDDEN / 128);
  short* lb0w = &lB0[brow * 40 + half * 16];
  short* lb1w = &lB1[brow * 40 + half * 16];

  f32x4 acc0[4][4], acc1[4][4];
  #pragma unroll
  for (int i = 0; i < 4; ++i)
    #pragma unroll
    for (int j = 0; j < 4; ++j){ acc0[i][j] = (f32x4)0.f; acc1[i][j] = (f32x4)0.f; }

  const int wm = tid >> 7, wn = (tid >> 6) & 1;
  const int cc = lane & 15, ks = lane >> 4;

  for (int kt = 0; kt < HIDDEN / 32; ++kt){
    gld16(arow0 + kt * 32, ldsA0);
    gld16(arow1 + kt * 32, ldsA1);
    {
      float sc = s0row[kt >> 2];
      const float* g = w0row + kt * 32;
      f32x4 q0 = *(const f32x4*)g,       q1 = *(const f32x4*)(g + 4),
            q2 = *(const f32x4*)(g + 8), q3 = *(const f32x4*)(g + 12);
      bf16x8 h0, h1;
      #pragma unroll
      for (int i = 0; i < 4; ++i){
        h0[i] = f2bf(q0[i] * sc); h0[4 + i] = f2bf(q1[i] * sc);
        h1[i] = f2bf(q2[i] * sc); h1[4 + i] = f2bf(q3[i] * sc);
      }
      *(bf16x8*)lb0w = h0; *(bf16x8*)(lb0w + 8) = h1;
    }
    {
      float sc = s1row[kt >> 2];
      const float* g = w1row + kt * 32;
      f32x4 q0 = *(const f32x4*)g,       q1 = *(const f32x4*)(g + 4),
            q2 = *(const f32x4*)(g + 8), q3 = *(const f32x4*)(g + 12);
      bf16x8 h0, h1;
      #pragma unroll
      for (int i = 0; i < 4; ++i){
        h0[i] = f2bf(q0[i] * sc); h0[4 + i] = f2bf(q1[i] * sc);
        h1[i] = f2bf(q2[i] * sc); h1[4 + i] = f2bf(q3[i] * sc);
      }
      *(bf16x8*)lb1w = h0; *(bf16x8*)(lb1w + 8) = h1;
    }
    __syncthreads();

    bf16x8 af[4];
    #pragma unroll
    for (int mf = 0; mf < 4; ++mf){
      int row = wm * 64 + mf * 16 + cc;
      af[mf] = *(const bf16x8*)&lA[row * 32 + ((ks ^ ((row >> 1) & 3)) * 8)];
    }
    #pragma unroll
    for (int nf = 0; nf < 4; ++nf){
      int rb = wn * 64 + nf * 16 + cc;
      bf16x8 b0 = *(const bf16x8*)&lB0[rb * 40 + ks * 8];
      bf16x8 b1 = *(const bf16x8*)&lB1[rb * 40 + ks * 8];
      #pragma unroll
      for (int mf = 0; mf < 4; ++mf)
        acc0[mf][nf] = __builtin_amdgcn_mfma_f32_16x16x32_bf16(af[mf], b0, acc0[mf][nf], 0, 0, 0);
      #pragma unroll
      for (int mf = 0; mf < 4; ++mf)
        acc1[mf][nf] = __builtin_amdgcn_mfma_f32_16x16x32_bf16(af[mf], b1, acc1[mf][nf], 0, 0, 0);
    }
    __syncthreads();
  }

  const int rbase = wm * 64 + (lane >> 4) * 4;
  #pragma unroll
  for (int mf = 0; mf < 4; ++mf){
    #pragma unroll
    for (int j = 0; j < 4; ++j){
      int row = rbase + mf * 16 + j;
      if (row < vr){
        short* ar = act + (size_t)(mstart + row) * INTER + blockIdx.y * BM + wn * 64 + cc;
        #pragma unroll
        for (int nf = 0; nf < 4; ++nf){
          float g = acc0[mf][nf][j], u = acc1[mf][nf][j];
          float a = g / (1.f + __expf(-g)) * u;
          ar[nf * 16] = f2bf(a);
        }
      }
    }
  }
}

__global__ __launch_bounds__(256) void k_gemm2(
    const short* __restrict__ act,
    const float* __restrict__ w2, const float* __restrict__ s2,
    const int2* __restrict__ tiles, const int* __restrict__ ntiles,
    const int* __restrict__ pair_tk, float* __restrict__ out)
{
  if ((int)blockIdx.x >= *ntiles) return;
  const int2 td = tiles[blockIdx.x];
  const int mstart = td.x;
  const int e  = td.y >> 16;
  const int vr = td.y & 0xFFFF;
  const int tid = threadIdx.x;
  const int lane = tid & 63;

  __shared__ short lA[BM * 32];
  __shared__ short lB[BM * 40];

  const int r0 = tid >> 2, r1 = 64 + (tid >> 2);
  const int seg = tid & 3;
  int p0 = mstart + r0; if (p0 >= NPAIR) p0 = NPAIR - 1;
  int p1 = mstart + r1; if (p1 >= NPAIR) p1 = NPAIR - 1;
  const short* arow0 = act + (size_t)p0 * INTER + (seg ^ ((r0 >> 1) & 3)) * 8;
  const short* arow1 = act + (size_t)p1 * INTER + (seg ^ ((r1 >> 1) & 3)) * 8;
  const short* ldsA0 = &lA[tid * 8];
  const short* ldsA1 = &lA[2048 + tid * 8];

  const int brow = tid >> 1, half = tid & 1;
  const int gbrow = blockIdx.y * BM + brow;
  const float* w2row = w2 + ((size_t)e * HIDDEN + gbrow) * INTER + half * 16;
  const float* s2row = s2 + ((size_t)e * HIDDEN + gbrow) * 11;
  short* lbw = &lB[brow * 40 + half * 16];

  f32x4 acc[4][4];
  #pragma unroll
  for (int i = 0; i < 4; ++i)
    #pragma unroll
    for (int j = 0; j < 4; ++j) acc[i][j] = (f32x4)0.f;

  const int wm = tid >> 7, wn = (tid >> 6) & 1;
  const int cc = lane & 15, ks = lane >> 4;

  for (int kt = 0; kt < INTER / 32; ++kt){
    gld16(arow0 + kt * 32, ldsA0);
    gld16(arow1 + kt * 32, ldsA1);
    {
      float sc = s2row[kt >> 2];
      const float* g = w2row + kt * 32;
      f32x4 q0 = *(const f32x4*)g,       q1 = *(const f32x4*)(g + 4),
            q2 = *(const f32x4*)(g + 8), q3 = *(const f32x4*)(g + 12);
      bf16x8 h0, h1;
      #pragma unroll
      for (int i = 0; i < 4; ++i){
        h0[i] = f2bf(q0[i] * sc); h0[4 + i] = f2bf(q1[i] * sc);
        h1[i] = f2bf(q2[i] * sc); h1[4 + i] = f2bf(q3[i] * sc);
      }
      *(bf16x8*)lbw = h0; *(bf16x8*)(lbw + 8) = h1;
    }
    __syncthreads();

    bf16x8 af[4];
    #pragma unroll
    for (int mf = 0; mf < 4; ++mf){
      int row = wm * 64 + mf * 16 + cc;
      af[mf] = *(const bf16x8*)&lA[row * 32 + ((ks ^ ((row >> 1) & 3)) * 8)];
    }
    #pragma unroll
    for (int nf = 0; nf < 4; ++nf){
      int rb = wn * 64 + nf * 16 + cc;
      bf16x8 b = *(const bf16x8*)&lB[rb * 40 + ks * 8];
      #pragma unroll
      for (int mf = 0; mf < 4; ++mf)
        acc[mf][nf] = __builtin_amdgcn_mfma_f32_16x16x32_bf16(af[mf], b, acc[mf][nf], 0, 0, 0);
    }
    __syncthreads();
  }

  const int rbase = wm * 64 + (lane >> 4) * 4;
  #pragma unroll
  for (int mf = 0; mf < 4; ++mf){
    #pragma unroll
    for (int j = 0; j < 4; ++j){
      int row = rbase + mf * 16 + j;
      if (row < vr){
        int ptk = pair_tk[mstart + row];
        float* orow = out + ((size_t)(ptk >> 3) * TOPK + (ptk & 7)) * HIDDEN
                      + blockIdx.y * BM + wn * 64 + cc;
        #pragma unroll
        for (int nf = 0; nf < 4; ++nf)
          orow[nf * 16] = acc[mf][nf][j];
      }
    }
  }
}

// ---------------- host ----------------

extern "C" void kernel_launch(void* const* d_in, const int* in_sizes, int n_in,
                              void* d_out, int out_size, void* d_ws, size_t ws_size,
                              hipStream_t stream)
{
  const float* x  = (const float*)d_in[0];
  const int*   sel= (const int*)  d_in[1];
  const float* w0 = (const float*)d_in[2];
  const float* s0 = (const float*)d_in[3];
  const float* w1 = (const float*)d_in[4];
  const float* s1 = (const float*)d_in[5];
  const float* w2 = (const float*)d_in[6];
  const float* s2 = (const float*)d_in[7];
  float* out = (float*)d_out;

  char* ws = (char*)d_ws;
  size_t o = 0;
  auto alloc = [&](size_t n){ size_t r = o; o = (o + n + 255) & ~(size_t)255; return r; };
  int*  cnt     = (int*) (ws + alloc(64));
  int*  cursor  = (int*) (ws + alloc(64));
  int*  offsets = (int*) (ws + alloc(68));
  int*  ntiles  = (int*) (ws + alloc(4));
  int*  ntiles2 = (int*) (ws + alloc(4));
  int2* tiles   = (int2*)(ws + alloc(MAXTILES * 8));
  int2* tiles2  = (int2*)(ws + alloc(MAXT2 * 8));
  int*  pair_tk = (int*) (ws + alloc((size_t)NPAIR * 4));
  short* xb     = (short*)(ws + alloc((size_t)TOKENS * HIDDEN * 2));
  short* act    = (short*)(ws + alloc((size_t)NPAIR * INTER * 2));
  const size_t WSZ = (size_t)NEXP * INTER * HIDDEN * 2;   // 92.27 MB each
  short* w0b    = (short*)(ws + alloc(WSZ));
  short* w1b    = (short*)(ws + alloc(WSZ));
  short* w2b    = (short*)(ws + alloc(WSZ));
  const bool predeq = (ws_size >= o);
  (void)in_sizes; (void)n_in; (void)out_size;

  hipMemsetAsync(ws, 0, 512, stream);   // cnt + cursor

  k_xcast  <<<(TOKENS * HIDDEN) / (256 * 8), 256, 0, stream>>>(x, xb);
  k_count  <<<(NPAIR + 255) / 256, 256, 0, stream>>>(sel, cnt);
  k_scan   <<<1, 64, 0, stream>>>(cnt, offsets, tiles, ntiles, tiles2, ntiles2);
  k_scatter<<<(NPAIR + 255) / 256, 256, 0, stream>>>(sel, offsets, cursor, pair_tk);

  if (predeq){
    // dequant w0+w1 merged; w2 dequant folded into g1's tail (see k_g1)
    k_deq01<<<2 * NEXP * INTER, 256, 0, stream>>>(w0, s0, w1, s1, w0b, w1b);
    k_g1<<<dim3(MAXT2, NT1), 512, 0, stream>>>(xb, w0b, w1b,
                                               tiles2, ntiles2, pair_tk, act,
                                               w2, s2, w2b);
    k_g2<<<dim3(MAXT2, NT2W), 512, 0, stream>>>(act, w2b,
                                                tiles2, ntiles2, pair_tk, out);
  } else {
    k_gemm1<<<dim3(MAXTILES, NT1), 256, 0, stream>>>(xb, w0, s0, w1, s1,
                                                     tiles, ntiles, pair_tk, act);
    k_gemm2<<<dim3(MAXTILES, NT2), 256, 0, stream>>>(act, w2, s2,
                                                     tiles, ntiles, pair_tk, out);
  }
}

// Round 10
// 826.180 us; speedup vs baseline: 1.0449x; 1.0449x over previous
//
#include <hip/hip_runtime.h>
#include <stdint.h>

#define TOKENS 4096
#define HIDDEN 2048
#define INTER  1408
#define NEXP   16
#define TOPK   6
#define NPAIR  (TOKENS*TOPK)          // 24576
#define BM     128
#define MAXTILES (NPAIR/BM + NEXP)    // 208 (128-row tiles, fallback path)
#define MAXT2  (NPAIR/256 + NEXP)     // 112 (256-row tiles, main path)
#define NT1    (INTER/128)            // 11
#define NT2    (HIDDEN/128)           // 16 (fallback)
#define NT2W   (HIDDEN/256)           // 8  (wide g2)

typedef __attribute__((ext_vector_type(8))) short bf16x8;
typedef __attribute__((ext_vector_type(4))) float f32x4;

__device__ __forceinline__ short f2bf(float f){
  union { float f; uint32_t u; } v; v.f = f;
  uint32_t r = (v.u + 0x7FFFu + ((v.u >> 16) & 1u)) >> 16;
  return (short)(r & 0xFFFFu);
}

__device__ __forceinline__ void gld16(const void* g, const void* l){
  __builtin_amdgcn_global_load_lds((const __attribute__((address_space(1))) void*)g,
                                   (__attribute__((address_space(3))) void*)l, 16, 0, 0);
}

__device__ __forceinline__ f32x4 ntld4(const float* p){
  return __builtin_nontemporal_load((const f32x4*)p);
}

#define SB() __builtin_amdgcn_sched_barrier(0)
#define BAR() __builtin_amdgcn_s_barrier()
#define WAITV(n) asm volatile("s_waitcnt vmcnt(" #n ")" ::: "memory")
#define WAITL() asm volatile("s_waitcnt lgkmcnt(0)" ::: "memory")

// ---------------- setup kernels ----------------

__global__ void k_xcast(const float* __restrict__ x, short* __restrict__ xb){
  int i = (blockIdx.x * 256 + threadIdx.x) * 8;
  f32x4 a = ntld4(x + i);
  f32x4 b = ntld4(x + i + 4);
  bf16x8 o;
  #pragma unroll
  for (int j = 0; j < 4; ++j){ o[j] = f2bf(a[j]); o[4+j] = f2bf(b[j]); }
  *(bf16x8*)(xb + i) = o;
}

// merged w0+w1 dequant: one row per block
__global__ void k_deq01(const float* __restrict__ w0, const float* __restrict__ s0,
                        const float* __restrict__ w1, const float* __restrict__ s1,
                        short* __restrict__ o0, short* __restrict__ o1){
  int row = blockIdx.x;
  const float* w; const float* s; short* o;
  if (row < NEXP * INTER){ w = w0; s = s0; o = o0; }
  else { row -= NEXP * INTER; w = w1; s = s1; o = o1; }
  const size_t base = (size_t)row * HIDDEN;
  const int c = threadIdx.x * 8;
  float sc = s[(size_t)row * (HIDDEN/128) + (c >> 7)];
  f32x4 a = ntld4(w + base + c);
  f32x4 b = ntld4(w + base + c + 4);
  bf16x8 h;
  #pragma unroll
  for (int j = 0; j < 4; ++j){ h[j] = f2bf(a[j] * sc); h[4+j] = f2bf(b[j] * sc); }
  *(bf16x8*)(o + base + c) = h;
}

// legacy per-tensor dequant (fallback path)
__global__ void k_dequant(const float* __restrict__ w, const float* __restrict__ s,
                          short* __restrict__ o, int rowlen, int nblk){
  const int row = blockIdx.x;
  const size_t base = (size_t)row * rowlen;
  for (int c = threadIdx.x * 8; c < rowlen; c += blockDim.x * 8){
    float sc = s[(size_t)row * nblk + (c >> 7)];
    f32x4 a = *(const f32x4*)(w + base + c);
    f32x4 b = *(const f32x4*)(w + base + c + 4);
    bf16x8 h;
    #pragma unroll
    for (int j = 0; j < 4; ++j){ h[j] = f2bf(a[j] * sc); h[4+j] = f2bf(b[j] * sc); }
    *(bf16x8*)(o + base + c) = h;
  }
}

__global__ void k_count(const int* __restrict__ sel, int* __restrict__ cnt){
  int p = blockIdx.x * 256 + threadIdx.x;
  if (p < NPAIR) atomicAdd(&cnt[sel[p]], 1);
}

__global__ void k_scan(const int* __restrict__ cnt, int* __restrict__ offsets,
                       int2* __restrict__ tiles, int* __restrict__ ntiles,
                       int2* __restrict__ tiles2, int* __restrict__ ntiles2){
  if (threadIdx.x != 0) return;
  int off = 0, nt = 0, nt2 = 0;
  for (int e = 0; e < NEXP; ++e){
    offsets[e] = off;
    int c = cnt[e];
    for (int m = 0; m < c; m += BM){
      int rows = c - m; if (rows > BM) rows = BM;
      tiles[nt++] = make_int2(off + m, (e << 16) | rows);
    }
    for (int m = 0; m < c; m += 256){
      int rows = c - m; if (rows > 256) rows = 256;
      tiles2[nt2++] = make_int2(off + m, (e << 16) | rows);
    }
    off += c;
  }
  offsets[NEXP] = off;
  *ntiles = nt;
  *ntiles2 = nt2;
}

__global__ void k_scatter(const int* __restrict__ sel, const int* __restrict__ offsets,
                          int* __restrict__ cursor, int* __restrict__ pair_tk){
  int p = blockIdx.x * 256 + threadIdx.x;
  if (p >= NPAIR) return;
  int e = sel[p];
  int pos = offsets[e] + atomicAdd(&cursor[e], 1);
  pair_tk[pos] = (p / TOPK) * 8 + (p % TOPK);   // t<<3 | slot
}

// ======== main path: 256-row tiles, BK=64, 512 thr, K-half-region pipeline,
// ======== 16x16x32 MFMA (32x32 tried r9: 4-way LDS aliasing, reverted)
// LDS layout [buf*2+kh][rows*32 shorts]; region contiguous -> global_load_lds
// linear. Granule XOR swizzle (both sides): LDS pos p in row r holds global
// granule p ^ ((r>>1)&3); ds_read sx = (ks ^ ((cc>>1)&3))*8 -> 2 lanes/bank,
// conflict-free (r7/r8 verified: SQ_LDS_BANK_CONFLICT = 0).
// Schedule: phase (t,0) stages (t+1,kh1), phase (t,1) stages (t+2,kh0);
// region consumed 3 phases after issue; counted vmcnt (never 0 mid-loop).

__global__ __launch_bounds__(512) void k_g1(
    const short* __restrict__ xb,
    const short* __restrict__ w0b, const short* __restrict__ w1b,
    const int2* __restrict__ tiles2, const int* __restrict__ ntiles2,
    const int* __restrict__ pair_tk, short* __restrict__ act,
    const float* __restrict__ w2, const float* __restrict__ s2,
    short* __restrict__ w2b)
{
  const int nwg = MAXT2 * NT1;                 // 1232, %8==0
  const int orig = (int)(blockIdx.y * MAXT2 + blockIdx.x);
  const int wg = (orig & 7) * (nwg >> 3) + (orig >> 3);
  const int tx = wg % MAXT2, ty = wg / MAXT2;
  const int tid = threadIdx.x, w = tid >> 6, lane = tid & 63;

  __shared__ short lA[4][8192];   // [buf*2+kh][256 rows * 32 shorts] = 16KB each
  __shared__ short lB[4][8192];

  if (tx < *ntiles2){
    const int2 td = tiles2[tx];
    const int mstart = td.x;
    const int e  = td.y >> 16;
    const int vr = td.y & 0xFFFF;

    const short* pA[2]; const short* pB[2]; int sg8[2];
    #pragma unroll
    for (int i = 0; i < 2; ++i){
      int s = (w * 2 + i) * 64 + lane;
      int r = s >> 2, j = (s & 3) ^ ((s >> 3) & 3);
      sg8[i] = s * 8;
      int p = mstart + r; if (p >= NPAIR) p = NPAIR - 1;
      pA[i] = xb + (size_t)(pair_tk[p] >> 3) * HIDDEN + j * 8;
      int G = r >> 4, srow = (G >> 1) * 16 + (r & 15);
      const short* wsrc = (G & 1) ? w1b : w0b;
      pB[i] = wsrc + ((size_t)e * INTER + (size_t)ty * 128 + srow) * HIDDEN + j * 8;
    }
    auto stage = [&](int slot, int ko){     // ko = tile*64 + kh*32 (shorts)
      #pragma unroll
      for (int i = 0; i < 2; ++i) gld16(pA[i] + ko, &lA[slot][sg8[i]]);
      #pragma unroll
      for (int i = 0; i < 2; ++i) gld16(pB[i] + ko, &lB[slot][sg8[i]]);
    };

    f32x4 acc[4][8];
    #pragma unroll
    for (int i = 0; i < 4; ++i)
      #pragma unroll
      for (int j = 0; j < 8; ++j) acc[i][j] = (f32x4)0.f;

    const int cc = lane & 15, ks = lane >> 4;
    const int sx = (ks ^ ((cc >> 1) & 3)) * 8;
    const int wm = w >> 1, wn = w & 1;
    int arow[4], brow[8];
    #pragma unroll
    for (int mf = 0; mf < 4; ++mf) arow[mf] = (wm * 64 + mf * 16 + cc) * 32;
    #pragma unroll
    for (int nf = 0; nf < 8; ++nf) brow[nf] = (wn * 128 + nf * 16 + cc) * 32;

    stage(0, 0); stage(1, 32); stage(2, 64); stage(3, 96);

    #pragma unroll 1
    for (int t = 0; t < 32; ++t){
      const int b = t & 1;
      // ---------- phase h=0: read slot b*2 ----------
      if (t == 0)      { WAITV(12); }
      else if (t < 31) { WAITV(8);  }
      else             { WAITV(4);  }
      SB(); BAR(); SB();
      {
        bf16x8 a0[4], bb[8];
        #pragma unroll
        for (int mf = 0; mf < 4; ++mf) a0[mf] = *(const bf16x8*)&lA[b*2][arow[mf] + sx];
        #pragma unroll
        for (int nf = 0; nf < 8; ++nf) bb[nf] = *(const bf16x8*)&lB[b*2][brow[nf] + sx];
        if (t >= 1 && t + 1 < 32) stage(((t+1)&1)*2 + 1, (t+1)*64 + 32);
        WAITL(); SB();
        __builtin_amdgcn_s_setprio(1);
        #pragma unroll
        for (int nf = 0; nf < 8; ++nf)
          #pragma unroll
          for (int mf = 0; mf < 4; ++mf)
            acc[mf][nf] = __builtin_amdgcn_mfma_f32_16x16x32_bf16(a0[mf], bb[nf], acc[mf][nf], 0, 0, 0);
        __builtin_amdgcn_s_setprio(0);
        SB(); BAR(); SB();
      }
      // ---------- phase h=1: read slot b*2+1 ----------
      if (t < 31) { WAITV(8); } else { WAITV(0); }
      SB(); BAR(); SB();
      {
        bf16x8 a0[4], bb[8];
        #pragma unroll
        for (int mf = 0; mf < 4; ++mf) a0[mf] = *(const bf16x8*)&lA[b*2+1][arow[mf] + sx];
        #pragma unroll
        for (int nf = 0; nf < 8; ++nf) bb[nf] = *(const bf16x8*)&lB[b*2+1][brow[nf] + sx];
        if (t + 2 < 32) stage(b*2, (t+2)*64);
        WAITL(); SB();
        __builtin_amdgcn_s_setprio(1);
        #pragma unroll
        for (int nf = 0; nf < 8; ++nf)
          #pragma unroll
          for (int mf = 0; mf < 4; ++mf)
            acc[mf][nf] = __builtin_amdgcn_mfma_f32_16x16x32_bf16(a0[mf], bb[nf], acc[mf][nf], 0, 0, 0);
        __builtin_amdgcn_s_setprio(0);
        SB(); BAR(); SB();
      }
    }

    // epilogue: pair (gate=acc[mf][2q], up=acc[mf][2q+1]) -> act col (wn*4+q)*16+cc
    #pragma unroll
    for (int mf = 0; mf < 4; ++mf){
      #pragma unroll
      for (int j = 0; j < 4; ++j){
        int row = wm * 64 + mf * 16 + ks * 4 + j;
        if (row < vr){
          short* ar = act + (size_t)(mstart + row) * INTER + (size_t)ty * 128 + cc;
          #pragma unroll
          for (int q = 0; q < 4; ++q){
            float g = acc[mf][2*q][j], u = acc[mf][2*q+1][j];
            float a = g / (1.f + __expf(-g)) * u;
            ar[(wn * 4 + q) * 16] = f2bf(a);
          }
        }
      }
    }
  }

  // ---- w2 dequant tail (all blocks; hides in g1 tail imbalance; g2 after) ----
  {
    const int total = NEXP * HIDDEN * (INTER / 8);   // 5,767,168 granules
    for (int gi = orig * 512 + tid; gi < total; gi += nwg * 512){
      int row = gi / (INTER / 8);
      int c = (gi - row * (INTER / 8)) * 8;
      const size_t base = (size_t)row * INTER;
      float sc = s2[(size_t)row * 11 + (c >> 7)];
      f32x4 a = ntld4(w2 + base + c);
      f32x4 b = ntld4(w2 + base + c + 4);
      bf16x8 h;
      #pragma unroll
      for (int j = 0; j < 4; ++j){ h[j] = f2bf(a[j] * sc); h[4+j] = f2bf(b[j] * sc); }
      *(bf16x8*)(w2b + base + c) = h;
    }
  }
}

// gemm2 WIDE: BN=256, 16x16x32 MFMA (same density as g1)
__global__ __launch_bounds__(512) void k_g2(
    const short* __restrict__ act, const short* __restrict__ w2b,
    const int2* __restrict__ tiles2, const int* __restrict__ ntiles2,
    const int* __restrict__ pair_tk, float* __restrict__ out)
{
  const int nwg = MAXT2 * NT2W;                // 896, %8==0
  const int orig = (int)(blockIdx.y * MAXT2 + blockIdx.x);
  const int wg = (orig & 7) * (nwg >> 3) + (orig >> 3);
  const int tx = wg % MAXT2, ty = wg / MAXT2;
  if (tx >= *ntiles2) return;
  const int2 td = tiles2[tx];
  const int mstart = td.x;
  const int e  = td.y >> 16;
  const int vr = td.y & 0xFFFF;

  __shared__ short lA[4][8192];
  __shared__ short lB[4][8192];

  const int tid = threadIdx.x, w = tid >> 6, lane = tid & 63;

  const short* pA[2]; const short* pB[2]; int sg8[2];
  #pragma unroll
  for (int i = 0; i < 2; ++i){
    int s = (w * 2 + i) * 64 + lane;
    int r = s >> 2, j = (s & 3) ^ ((s >> 3) & 3);
    sg8[i] = s * 8;
    int p = mstart + r; if (p >= NPAIR) p = NPAIR - 1;
    pA[i] = act + (size_t)p * INTER + j * 8;
    pB[i] = w2b + ((size_t)e * HIDDEN + (size_t)ty * 256 + r) * INTER + j * 8;
  }
  auto stage = [&](int slot, int ko){
    #pragma unroll
    for (int i = 0; i < 2; ++i) gld16(pA[i] + ko, &lA[slot][sg8[i]]);
    #pragma unroll
    for (int i = 0; i < 2; ++i) gld16(pB[i] + ko, &lB[slot][sg8[i]]);
  };

  f32x4 acc[4][8];
  #pragma unroll
  for (int i = 0; i < 4; ++i)
    #pragma unroll
    for (int j = 0; j < 8; ++j) acc[i][j] = (f32x4)0.f;

  const int cc = lane & 15, ks = lane >> 4;
  const int sx = (ks ^ ((cc >> 1) & 3)) * 8;
  const int wm = w >> 1, wn = w & 1;
  int arow[4], brow[8];
  #pragma unroll
  for (int mf = 0; mf < 4; ++mf) arow[mf] = (wm * 64 + mf * 16 + cc) * 32;
  #pragma unroll
  for (int nf = 0; nf < 8; ++nf) brow[nf] = (wn * 128 + nf * 16 + cc) * 32;

  stage(0, 0); stage(1, 32); stage(2, 64); stage(3, 96);

  #pragma unroll 1
  for (int t = 0; t < 22; ++t){
    const int b = t & 1;
    // ---------- phase h=0: read slot b*2 ----------
    if (t == 0)      { WAITV(12); }
    else if (t < 21) { WAITV(8);  }
    else             { WAITV(4);  }
    SB(); BAR(); SB();
    {
      bf16x8 a0[4], bb[8];
      #pragma unroll
      for (int mf = 0; mf < 4; ++mf) a0[mf] = *(const bf16x8*)&lA[b*2][arow[mf] + sx];
      #pragma unroll
      for (int nf = 0; nf < 8; ++nf) bb[nf] = *(const bf16x8*)&lB[b*2][brow[nf] + sx];
      if (t >= 1 && t + 1 < 22) stage(((t+1)&1)*2 + 1, (t+1)*64 + 32);
      WAITL(); SB();
      __builtin_amdgcn_s_setprio(1);
      #pragma unroll
      for (int nf = 0; nf < 8; ++nf)
        #pragma unroll
        for (int mf = 0; mf < 4; ++mf)
          acc[mf][nf] = __builtin_amdgcn_mfma_f32_16x16x32_bf16(a0[mf], bb[nf], acc[mf][nf], 0, 0, 0);
      __builtin_amdgcn_s_setprio(0);
      SB(); BAR(); SB();
    }
    // ---------- phase h=1: read slot b*2+1 ----------
    if (t < 21) { WAITV(8); } else { WAITV(0); }
    SB(); BAR(); SB();
    {
      bf16x8 a0[4], bb[8];
      #pragma unroll
      for (int mf = 0; mf < 4; ++mf) a0[mf] = *(const bf16x8*)&lA[b*2+1][arow[mf] + sx];
      #pragma unroll
      for (int nf = 0; nf < 8; ++nf) bb[nf] = *(const bf16x8*)&lB[b*2+1][brow[nf] + sx];
      if (t + 2 < 22) stage(b*2, (t+2)*64);
      WAITL(); SB();
      __builtin_amdgcn_s_setprio(1);
      #pragma unroll
      for (int nf = 0; nf < 8; ++nf)
        #pragma unroll
        for (int mf = 0; mf < 4; ++mf)
          acc[mf][nf] = __builtin_amdgcn_mfma_f32_16x16x32_bf16(a0[mf], bb[nf], acc[mf][nf], 0, 0, 0);
      __builtin_amdgcn_s_setprio(0);
      SB(); BAR(); SB();
    }
  }

  #pragma unroll
  for (int mf = 0; mf < 4; ++mf){
    #pragma unroll
    for (int j = 0; j < 4; ++j){
      int row = wm * 64 + mf * 16 + ks * 4 + j;
      if (row < vr){
        int ptk = pair_tk[mstart + row];
        float* orow = out + ((size_t)(ptk >> 3) * TOPK + (ptk & 7)) * HIDDEN
                      + (size_t)ty * 256 + wn * 128 + cc;
        #pragma unroll
        for (int nf = 0; nf < 8; ++nf)
          orow[nf * 16] = acc[mf][nf][j];
      }
    }
  }
}

// ======== fallback GEMMs (in-GEMM dequant, round-1 proven) ========

__global__ __launch_bounds__(256) void k_gemm1(
    const short* __restrict__ xb,
    const float* __restrict__ w0, const float* __restrict__ s0,
    const float* __restrict__ w1, const float* __restrict__ s1,
    const int2* __restrict__ tiles, const int* __restrict__ ntiles,
    const int* __restrict__ pair_tk, short* __restrict__ act)
{
  if ((int)blockIdx.x >= *ntiles) return;
  const int2 td = tiles[blockIdx.x];
  const int mstart = td.x;
  const int e  = td.y >> 16;
  const int vr = td.y & 0xFFFF;
  const int tid = threadIdx.x;
  const int lane = tid & 63;

  __shared__ short lA[BM * 32];
  __shared__ short lB0[BM * 40];
  __shared__ short lB1[BM * 40];

  const int r0 = tid >> 2, r1 = 64 + (tid >> 2);
  const int seg = tid & 3;
  int p0 = mstart + r0; if (p0 >= NPAIR) p0 = NPAIR - 1;
  int p1 = mstart + r1; if (p1 >= NPAIR) p1 = NPAIR - 1;
  const short* arow0 = xb + (size_t)(pair_tk[p0] >> 3) * HIDDEN + (seg ^ ((r0 >> 1) & 3)) * 8;
  const short* arow1 = xb + (size_t)(pair_tk[p1] >> 3) * HIDDEN + (seg ^ ((r1 >> 1) & 3)) * 8;
  const short* ldsA0 = &lA[tid * 8];
  const short* ldsA1 = &lA[2048 + tid * 8];

  const int brow = tid >> 1, half = tid & 1;
  const int gbrow = blockIdx.y * BM + brow;
  const float* w0row = w0 + ((size_t)e * INTER + gbrow) * HIDDEN + half * 16;
  const float* w1row = w1 + ((size_t)e * INTER + gbrow) * HIDDEN + half * 16;
  const float* s0row = s0 + ((size_t)e * INTER + gbrow) * (HIDDEN / 128);
  const float* s1row = s1 + ((size_t)e * INTER + gbrow) * (HIDDEN / 128);
  short* lb0w = &lB0[brow * 40 + half * 16];
  short* lb1w = &lB1[brow * 40 + half * 16];

  f32x4 acc0[4][4], acc1[4][4];
  #pragma unroll
  for (int i = 0; i < 4; ++i)
    #pragma unroll
    for (int j = 0; j < 4; ++j){ acc0[i][j] = (f32x4)0.f; acc1[i][j] = (f32x4)0.f; }

  const int wm = tid >> 7, wn = (tid >> 6) & 1;
  const int cc = lane & 15, ks = lane >> 4;

  for (int kt = 0; kt < HIDDEN / 32; ++kt){
    gld16(arow0 + kt * 32, ldsA0);
    gld16(arow1 + kt * 32, ldsA1);
    {
      float sc = s0row[kt >> 2];
      const float* g = w0row + kt * 32;
      f32x4 q0 = *(const f32x4*)g,       q1 = *(const f32x4*)(g + 4),
            q2 = *(const f32x4*)(g + 8), q3 = *(const f32x4*)(g + 12);
      bf16x8 h0, h1;
      #pragma unroll
      for (int i = 0; i < 4; ++i){
        h0[i] = f2bf(q0[i] * sc); h0[4 + i] = f2bf(q1[i] * sc);
        h1[i] = f2bf(q2[i] * sc); h1[4 + i] = f2bf(q3[i] * sc);
      }
      *(bf16x8*)lb0w = h0; *(bf16x8*)(lb0w + 8) = h1;
    }
    {
      float sc = s1row[kt >> 2];
      const float* g = w1row + kt * 32;
      f32x4 q0 = *(const f32x4*)g,       q1 = *(const f32x4*)(g + 4),
            q2 = *(const f32x4*)(g + 8), q3 = *(const f32x4*)(g + 12);
      bf16x8 h0, h1;
      #pragma unroll
      for (int i = 0; i < 4; ++i){
        h0[i] = f2bf(q0[i] * sc); h0[4 + i] = f2bf(q1[i] * sc);
        h1[i] = f2bf(q2[i] * sc); h1[4 + i] = f2bf(q3[i] * sc);
      }
      *(bf16x8*)lb1w = h0; *(bf16x8*)(lb1w + 8) = h1;
    }
    __syncthreads();

    bf16x8 af[4];
    #pragma unroll
    for (int mf = 0; mf < 4; ++mf){
      int row = wm * 64 + mf * 16 + cc;
      af[mf] = *(const bf16x8*)&lA[row * 32 + ((ks ^ ((row >> 1) & 3)) * 8)];
    }
    #pragma unroll
    for (int nf = 0; nf < 4; ++nf){
      int rb = wn * 64 + nf * 16 + cc;
      bf16x8 b0 = *(const bf16x8*)&lB0[rb * 40 + ks * 8];
      bf16x8 b1 = *(const bf16x8*)&lB1[rb * 40 + ks * 8];
      #pragma unroll
      for (int mf = 0; mf < 4; ++mf)
        acc0[mf][nf] = __builtin_amdgcn_mfma_f32_16x16x32_bf16(af[mf], b0, acc0[mf][nf], 0, 0, 0);
      #pragma unroll
      for (int mf = 0; mf < 4; ++mf)
        acc1[mf][nf] = __builtin_amdgcn_mfma_f32_16x16x32_bf16(af[mf], b1, acc1[mf][nf], 0, 0, 0);
    }
    __syncthreads();
  }

  const int rbase = wm * 64 + (lane >> 4) * 4;
  #pragma unroll
  for (int mf = 0; mf < 4; ++mf){
    #pragma unroll
    for (int j = 0; j < 4; ++j){
      int row = rbase + mf * 16 + j;
      if (row < vr){
        short* ar = act + (size_t)(mstart + row) * INTER + blockIdx.y * BM + wn * 64 + cc;
        #pragma unroll
        for (int nf = 0; nf < 4; ++nf){
          float g = acc0[mf][nf][j], u = acc1[mf][nf][j];
          float a = g / (1.f + __expf(-g)) * u;
          ar[nf * 16] = f2bf(a);
        }
      }
    }
  }
}

__global__ __launch_bounds__(256) void k_gemm2(
    const short* __restrict__ act,
    const float* __restrict__ w2, const float* __restrict__ s2,
    const int2* __restrict__ tiles, const int* __restrict__ ntiles,
    const int* __restrict__ pair_tk, float* __restrict__ out)
{
  if ((int)blockIdx.x >= *ntiles) return;
  const int2 td = tiles[blockIdx.x];
  const int mstart = td.x;
  const int e  = td.y >> 16;
  const int vr = td.y & 0xFFFF;
  const int tid = threadIdx.x;
  const int lane = tid & 63;

  __shared__ short lA[BM * 32];
  __shared__ short lB[BM * 40];

  const int r0 = tid >> 2, r1 = 64 + (tid >> 2);
  const int seg = tid & 3;
  int p0 = mstart + r0; if (p0 >= NPAIR) p0 = NPAIR - 1;
  int p1 = mstart + r1; if (p1 >= NPAIR) p1 = NPAIR - 1;
  const short* arow0 = act + (size_t)p0 * INTER + (seg ^ ((r0 >> 1) & 3)) * 8;
  const short* arow1 = act + (size_t)p1 * INTER + (seg ^ ((r1 >> 1) & 3)) * 8;
  const short* ldsA0 = &lA[tid * 8];
  const short* ldsA1 = &lA[2048 + tid * 8];

  const int brow = tid >> 1, half = tid & 1;
  const int gbrow = blockIdx.y * BM + brow;
  const float* w2row = w2 + ((size_t)e * HIDDEN + gbrow) * INTER + half * 16;
  const float* s2row = s2 + ((size_t)e * HIDDEN + gbrow) * 11;
  short* lbw = &lB[brow * 40 + half * 16];

  f32x4 acc[4][4];
  #pragma unroll
  for (int i = 0; i < 4; ++i)
    #pragma unroll
    for (int j = 0; j < 4; ++j) acc[i][j] = (f32x4)0.f;

  const int wm = tid >> 7, wn = (tid >> 6) & 1;
  const int cc = lane & 15, ks = lane >> 4;

  for (int kt = 0; kt < INTER / 32; ++kt){
    gld16(arow0 + kt * 32, ldsA0);
    gld16(arow1 + kt * 32, ldsA1);
    {
      float sc = s2row[kt >> 2];
      const float* g = w2row + kt * 32;
      f32x4 q0 = *(const f32x4*)g,       q1 = *(const f32x4*)(g + 4),
            q2 = *(const f32x4*)(g + 8), q3 = *(const f32x4*)(g + 12);
      bf16x8 h0, h1;
      #pragma unroll
      for (int i = 0; i < 4; ++i){
        h0[i] = f2bf(q0[i] * sc); h0[4 + i] = f2bf(q1[i] * sc);
        h1[i] = f2bf(q2[i] * sc); h1[4 + i] = f2bf(q3[i] * sc);
      }
      *(bf16x8*)lbw = h0; *(bf16x8*)(lbw + 8) = h1;
    }
    __syncthreads();

    bf16x8 af[4];
    #pragma unroll
    for (int mf = 0; mf < 4; ++mf){
      int row = wm * 64 + mf * 16 + cc;
      af[mf] = *(const bf16x8*)&lA[row * 32 + ((ks ^ ((row >> 1) & 3)) * 8)];
    }
    #pragma unroll
    for (int nf = 0; nf < 4; ++nf){
      int rb = wn * 64 + nf * 16 + cc;
      bf16x8 b = *(const bf16x8*)&lB[rb * 40 + ks * 8];
      #pragma unroll
      for (int mf = 0; mf < 4; ++mf)
        acc[mf][nf] = __builtin_amdgcn_mfma_f32_16x16x32_bf16(af[mf], b, acc[mf][nf], 0, 0, 0);
    }
    __syncthreads();
  }

  const int rbase = wm * 64 + (lane >> 4) * 4;
  #pragma unroll
  for (int mf = 0; mf < 4; ++mf){
    #pragma unroll
    for (int j = 0; j < 4; ++j){
      int row = rbase + mf * 16 + j;
      if (row < vr){
        int ptk = pair_tk[mstart + row];
        float* orow = out + ((size_t)(ptk >> 3) * TOPK + (ptk & 7)) * HIDDEN
                      + blockIdx.y * BM + wn * 64 + cc;
        #pragma unroll
        for (int nf = 0; nf < 4; ++nf)
          orow[nf * 16] = acc[mf][nf][j];
      }
    }
  }
}

// ---------------- host ----------------

extern "C" void kernel_launch(void* const* d_in, const int* in_sizes, int n_in,
                              void* d_out, int out_size, void* d_ws, size_t ws_size,
                              hipStream_t stream)
{
  const float* x  = (const float*)d_in[0];
  const int*   sel= (const int*)  d_in[1];
  const float* w0 = (const float*)d_in[2];
  const float* s0 = (const float*)d_in[3];
  const float* w1 = (const float*)d_in[4];
  const float* s1 = (const float*)d_in[5];
  const float* w2 = (const float*)d_in[6];
  const float* s2 = (const float*)d_in[7];
  float* out = (float*)d_out;

  char* ws = (char*)d_ws;
  size_t o = 0;
  auto alloc = [&](size_t n){ size_t r = o; o = (o + n + 255) & ~(size_t)255; return r; };
  int*  cnt     = (int*) (ws + alloc(64));
  int*  cursor  = (int*) (ws + alloc(64));
  int*  offsets = (int*) (ws + alloc(68));
  int*  ntiles  = (int*) (ws + alloc(4));
  int*  ntiles2 = (int*) (ws + alloc(4));
  int2* tiles   = (int2*)(ws + alloc(MAXTILES * 8));
  int2* tiles2  = (int2*)(ws + alloc(MAXT2 * 8));
  int*  pair_tk = (int*) (ws + alloc((size_t)NPAIR * 4));
  short* xb     = (short*)(ws + alloc((size_t)TOKENS * HIDDEN * 2));
  short* act    = (short*)(ws + alloc((size_t)NPAIR * INTER * 2));
  const size_t WSZ = (size_t)NEXP * INTER * HIDDEN * 2;   // 92.27 MB each
  short* w0b    = (short*)(ws + alloc(WSZ));
  short* w1b    = (short*)(ws + alloc(WSZ));
  short* w2b    = (short*)(ws + alloc(WSZ));
  const bool predeq = (ws_size >= o);
  (void)in_sizes; (void)n_in; (void)out_size;

  hipMemsetAsync(ws, 0, 512, stream);   // cnt + cursor

  k_xcast  <<<(TOKENS * HIDDEN) / (256 * 8), 256, 0, stream>>>(x, xb);
  k_count  <<<(NPAIR + 255) / 256, 256, 0, stream>>>(sel, cnt);
  k_scan   <<<1, 64, 0, stream>>>(cnt, offsets, tiles, ntiles, tiles2, ntiles2);
  k_scatter<<<(NPAIR + 255) / 256, 256, 0, stream>>>(sel, offsets, cursor, pair_tk);

  if (predeq){
    // dequant w0+w1 merged; w2 dequant folded into g1's tail (see k_g1)
    k_deq01<<<2 * NEXP * INTER, 256, 0, stream>>>(w0, s0, w1, s1, w0b, w1b);
    k_g1<<<dim3(MAXT2, NT1), 512, 0, stream>>>(xb, w0b, w1b,
                                               tiles2, ntiles2, pair_tk, act,
                                               w2, s2, w2b);
    k_g2<<<dim3(MAXT2, NT2W), 512, 0, stream>>>(act, w2b,
                                                tiles2, ntiles2, pair_tk, out);
  } else {
    k_gemm1<<<dim3(MAXTILES, NT1), 256, 0, stream>>>(xb, w0, s0, w1, s1,
                                                     tiles, ntiles, pair_tk, act);
    k_gemm2<<<dim3(MAXTILES, NT2), 256, 0, stream>>>(act, w2, s2,
                                                     tiles, ntiles, pair_tk, out);
  }
}

// Round 11
// 822.889 us; speedup vs baseline: 1.0491x; 1.0040x over previous
//
#include <hip/hip_runtime.h>
#include <stdint.h>

#define TOKENS 4096
#define HIDDEN 2048
#define INTER  1408
#define NEXP   16
#define TOPK   6
#define NPAIR  (TOKENS*TOPK)          // 24576
#define BM     128
#define MAXTILES (NPAIR/BM + NEXP)    // 208 (128-row tiles, fallback path)
#define MAXT2  (NPAIR/256 + NEXP)     // 112 (256-row tiles, main path)
#define NT1    (INTER/128)            // 11
#define NT2    (HIDDEN/128)           // 16 (fallback)
#define NT2W   (HIDDEN/256)           // 8  (wide g2)

typedef __attribute__((ext_vector_type(8))) short bf16x8;
typedef __attribute__((ext_vector_type(4))) float f32x4;

__device__ __forceinline__ short f2bf(float f){
  union { float f; uint32_t u; } v; v.f = f;
  uint32_t r = (v.u + 0x7FFFu + ((v.u >> 16) & 1u)) >> 16;
  return (short)(r & 0xFFFFu);
}

__device__ __forceinline__ void gld16(const void* g, const void* l){
  __builtin_amdgcn_global_load_lds((const __attribute__((address_space(1))) void*)g,
                                   (__attribute__((address_space(3))) void*)l, 16, 0, 0);
}

__device__ __forceinline__ f32x4 ntld4(const float* p){
  return __builtin_nontemporal_load((const f32x4*)p);
}

#define SB() __builtin_amdgcn_sched_barrier(0)
#define BAR() __builtin_amdgcn_s_barrier()
#define WAITV(n) asm volatile("s_waitcnt vmcnt(" #n ")" ::: "memory")
#define WAITL() asm volatile("s_waitcnt lgkmcnt(0)" ::: "memory")

// ---------------- setup kernels ----------------

// merged w0+w1 dequant + x->bf16 cast (one launch; traffic overlaps)
__global__ void k_deq01x(const float* __restrict__ x, short* __restrict__ xb,
                         const float* __restrict__ w0, const float* __restrict__ s0,
                         const float* __restrict__ w1, const float* __restrict__ s1,
                         short* __restrict__ o0, short* __restrict__ o1){
  int row = blockIdx.x;
  if (row >= 2 * NEXP * INTER){
    // xcast slice: 2048 f32 per block
    int i = ((row - 2 * NEXP * INTER) * 256 + threadIdx.x) * 8;
    f32x4 a = ntld4(x + i);
    f32x4 b = ntld4(x + i + 4);
    bf16x8 o;
    #pragma unroll
    for (int j = 0; j < 4; ++j){ o[j] = f2bf(a[j]); o[4+j] = f2bf(b[j]); }
    *(bf16x8*)(xb + i) = o;
    return;
  }
  const float* w; const float* s; short* o;
  if (row < NEXP * INTER){ w = w0; s = s0; o = o0; }
  else { row -= NEXP * INTER; w = w1; s = s1; o = o1; }
  const size_t base = (size_t)row * HIDDEN;
  const int c = threadIdx.x * 8;
  float sc = s[(size_t)row * (HIDDEN/128) + (c >> 7)];
  f32x4 a = ntld4(w + base + c);
  f32x4 b = ntld4(w + base + c + 4);
  bf16x8 h;
  #pragma unroll
  for (int j = 0; j < 4; ++j){ h[j] = f2bf(a[j] * sc); h[4+j] = f2bf(b[j] * sc); }
  *(bf16x8*)(o + base + c) = h;
}

// w2 dequant: flat grid-stride over 8-elem granules
__global__ void k_deqw2(const float* __restrict__ w2, const float* __restrict__ s2,
                        short* __restrict__ o){
  const int total = NEXP * HIDDEN * (INTER / 8);   // 5,767,168 granules
  for (int gi = blockIdx.x * 256 + threadIdx.x; gi < total; gi += gridDim.x * 256){
    int row = gi / (INTER / 8);
    int c = (gi - row * (INTER / 8)) * 8;
    const size_t base = (size_t)row * INTER;
    float sc = s2[(size_t)row * 11 + (c >> 7)];
    f32x4 a = ntld4(w2 + base + c);
    f32x4 b = ntld4(w2 + base + c + 4);
    bf16x8 h;
    #pragma unroll
    for (int j = 0; j < 4; ++j){ h[j] = f2bf(a[j] * sc); h[4+j] = f2bf(b[j] * sc); }
    *(bf16x8*)(o + base + c) = h;
  }
}

// legacy kernels (fallback path)
__global__ void k_xcast(const float* __restrict__ x, short* __restrict__ xb){
  int i = (blockIdx.x * 256 + threadIdx.x) * 8;
  f32x4 a = ntld4(x + i);
  f32x4 b = ntld4(x + i + 4);
  bf16x8 o;
  #pragma unroll
  for (int j = 0; j < 4; ++j){ o[j] = f2bf(a[j]); o[4+j] = f2bf(b[j]); }
  *(bf16x8*)(xb + i) = o;
}

__global__ void k_count(const int* __restrict__ sel, int* __restrict__ cnt){
  int p = blockIdx.x * 256 + threadIdx.x;
  if (p < NPAIR) atomicAdd(&cnt[sel[p]], 1);
}

__global__ void k_scan(const int* __restrict__ cnt, int* __restrict__ offsets,
                       int2* __restrict__ tiles, int* __restrict__ ntiles,
                       int2* __restrict__ tiles2, int* __restrict__ ntiles2){
  if (threadIdx.x != 0) return;
  int off = 0, nt = 0, nt2 = 0;
  for (int e = 0; e < NEXP; ++e){
    offsets[e] = off;
    int c = cnt[e];
    for (int m = 0; m < c; m += BM){
      int rows = c - m; if (rows > BM) rows = BM;
      tiles[nt++] = make_int2(off + m, (e << 16) | rows);
    }
    for (int m = 0; m < c; m += 256){
      int rows = c - m; if (rows > 256) rows = 256;
      tiles2[nt2++] = make_int2(off + m, (e << 16) | rows);
    }
    off += c;
  }
  offsets[NEXP] = off;
  *ntiles = nt;
  *ntiles2 = nt2;
}

__global__ void k_scatter(const int* __restrict__ sel, const int* __restrict__ offsets,
                          int* __restrict__ cursor, int* __restrict__ pair_tk){
  int p = blockIdx.x * 256 + threadIdx.x;
  if (p >= NPAIR) return;
  int e = sel[p];
  int pos = offsets[e] + atomicAdd(&cursor[e], 1);
  pair_tk[pos] = (p / TOPK) * 8 + (p % TOPK);   // t<<3 | slot
}

// ======== main path: 256-row tiles, BK=64, 512 thr, K-half-region pipeline,
// ======== 16x16x32 MFMA. LDS [buf*2+kh][rows*32 shorts]; region contiguous ->
// global_load_lds linear. Granule XOR swizzle (both sides): LDS pos p in row r
// holds global granule p ^ ((r>>1)&3); ds_read sx = (ks ^ ((cc>>1)&3))*8 ->
// 2 lanes/bank, conflict-free (r7/r8: SQ_LDS_BANK_CONFLICT = 0).
// Epilogue: LDS write-combine -> coalesced row stores (r11).

__global__ __launch_bounds__(512) void k_g1(
    const short* __restrict__ xb,
    const short* __restrict__ w0b, const short* __restrict__ w1b,
    const int2* __restrict__ tiles2, const int* __restrict__ ntiles2,
    const int* __restrict__ pair_tk, short* __restrict__ act)
{
  const int nwg = MAXT2 * NT1;                 // 1232, %8==0
  const int orig = (int)(blockIdx.y * MAXT2 + blockIdx.x);
  const int wg = (orig & 7) * (nwg >> 3) + (orig >> 3);
  const int tx = wg % MAXT2, ty = wg / MAXT2;
  if (tx >= *ntiles2) return;
  const int2 td = tiles2[tx];
  const int mstart = td.x;
  const int e  = td.y >> 16;
  const int vr = td.y & 0xFFFF;

  __shared__ short lmem[8][8192];              // 128 KB
  short (*lA)[8192] = lmem;                    // slots 0..3
  short (*lB)[8192] = lmem + 4;                // slots 0..3

  const int tid = threadIdx.x, w = tid >> 6, lane = tid & 63;

  const short* pA[2]; const short* pB[2]; int sg8[2];
  #pragma unroll
  for (int i = 0; i < 2; ++i){
    int s = (w * 2 + i) * 64 + lane;
    int r = s >> 2, j = (s & 3) ^ ((s >> 3) & 3);
    sg8[i] = s * 8;
    int p = mstart + r; if (p >= NPAIR) p = NPAIR - 1;
    pA[i] = xb + (size_t)(pair_tk[p] >> 3) * HIDDEN + j * 8;
    int G = r >> 4, srow = (G >> 1) * 16 + (r & 15);
    const short* wsrc = (G & 1) ? w1b : w0b;
    pB[i] = wsrc + ((size_t)e * INTER + (size_t)ty * 128 + srow) * HIDDEN + j * 8;
  }
  auto stage = [&](int slot, int ko){     // ko = tile*64 + kh*32 (shorts)
    #pragma unroll
    for (int i = 0; i < 2; ++i) gld16(pA[i] + ko, &lA[slot][sg8[i]]);
    #pragma unroll
    for (int i = 0; i < 2; ++i) gld16(pB[i] + ko, &lB[slot][sg8[i]]);
  };

  f32x4 acc[4][8];
  #pragma unroll
  for (int i = 0; i < 4; ++i)
    #pragma unroll
    for (int j = 0; j < 8; ++j) acc[i][j] = (f32x4)0.f;

  const int cc = lane & 15, ks = lane >> 4;
  const int sx = (ks ^ ((cc >> 1) & 3)) * 8;
  const int wm = w >> 1, wn = w & 1;
  int arow[4], brow[8];
  #pragma unroll
  for (int mf = 0; mf < 4; ++mf) arow[mf] = (wm * 64 + mf * 16 + cc) * 32;
  #pragma unroll
  for (int nf = 0; nf < 8; ++nf) brow[nf] = (wn * 128 + nf * 16 + cc) * 32;

  stage(0, 0); stage(1, 32); stage(2, 64); stage(3, 96);

  #pragma unroll 1
  for (int t = 0; t < 32; ++t){
    const int b = t & 1;
    // ---------- phase h=0: read slot b*2 ----------
    if (t == 0)      { WAITV(12); }
    else if (t < 31) { WAITV(8);  }
    else             { WAITV(4);  }
    SB(); BAR(); SB();
    {
      bf16x8 a0[4], bb[8];
      #pragma unroll
      for (int mf = 0; mf < 4; ++mf) a0[mf] = *(const bf16x8*)&lA[b*2][arow[mf] + sx];
      #pragma unroll
      for (int nf = 0; nf < 8; ++nf) bb[nf] = *(const bf16x8*)&lB[b*2][brow[nf] + sx];
      if (t >= 1 && t + 1 < 32) stage(((t+1)&1)*2 + 1, (t+1)*64 + 32);
      WAITL(); SB();
      __builtin_amdgcn_s_setprio(1);
      #pragma unroll
      for (int nf = 0; nf < 8; ++nf)
        #pragma unroll
        for (int mf = 0; mf < 4; ++mf)
          acc[mf][nf] = __builtin_amdgcn_mfma_f32_16x16x32_bf16(a0[mf], bb[nf], acc[mf][nf], 0, 0, 0);
      __builtin_amdgcn_s_setprio(0);
      SB(); BAR(); SB();
    }
    // ---------- phase h=1: read slot b*2+1 ----------
    if (t < 31) { WAITV(8); } else { WAITV(0); }
    SB(); BAR(); SB();
    {
      bf16x8 a0[4], bb[8];
      #pragma unroll
      for (int mf = 0; mf < 4; ++mf) a0[mf] = *(const bf16x8*)&lA[b*2+1][arow[mf] + sx];
      #pragma unroll
      for (int nf = 0; nf < 8; ++nf) bb[nf] = *(const bf16x8*)&lB[b*2+1][brow[nf] + sx];
      if (t + 2 < 32) stage(b*2, (t+2)*64);
      WAITL(); SB();
      __builtin_amdgcn_s_setprio(1);
      #pragma unroll
      for (int nf = 0; nf < 8; ++nf)
        #pragma unroll
        for (int mf = 0; mf < 4; ++mf)
          acc[mf][nf] = __builtin_amdgcn_mfma_f32_16x16x32_bf16(a0[mf], bb[nf], acc[mf][nf], 0, 0, 0);
      __builtin_amdgcn_s_setprio(0);
      SB(); BAR(); SB();
    }
  }

  // ---- epilogue: silu(gate)*up -> LDS [256][128] bf16 (64 KB), then
  // ---- coalesced 256-B row writes (wave w owns rows w*32..w*32+31)
  short* lT = (short*)lmem;
  __syncthreads();
  #pragma unroll
  for (int mf = 0; mf < 4; ++mf){
    #pragma unroll
    for (int j = 0; j < 4; ++j){
      int row = wm * 64 + mf * 16 + ks * 4 + j;
      #pragma unroll
      for (int q = 0; q < 4; ++q){
        float g = acc[mf][2*q][j], u = acc[mf][2*q+1][j];
        float a = g / (1.f + __expf(-g)) * u;
        lT[row * 128 + (wn * 4 + q) * 16 + cc] = f2bf(a);
      }
    }
  }
  __syncthreads();
  #pragma unroll 1
  for (int rr = 0; rr < 32; ++rr){
    int row = w * 32 + rr;
    if (row < vr){
      uint32_t v = *(const uint32_t*)&lT[row * 128 + lane * 2];
      *(uint32_t*)&act[(size_t)(mstart + row) * INTER + (size_t)ty * 128 + lane * 2] = v;
    }
  }
}

// gemm2 WIDE: BN=256, 16x16x32 MFMA; epilogue LDS write-combine (2 passes)
__global__ __launch_bounds__(512) void k_g2(
    const short* __restrict__ act, const short* __restrict__ w2b,
    const int2* __restrict__ tiles2, const int* __restrict__ ntiles2,
    const int* __restrict__ pair_tk, float* __restrict__ out)
{
  const int nwg = MAXT2 * NT2W;                // 896, %8==0
  const int orig = (int)(blockIdx.y * MAXT2 + blockIdx.x);
  const int wg = (orig & 7) * (nwg >> 3) + (orig >> 3);
  const int tx = wg % MAXT2, ty = wg / MAXT2;
  if (tx >= *ntiles2) return;
  const int2 td = tiles2[tx];
  const int mstart = td.x;
  const int e  = td.y >> 16;
  const int vr = td.y & 0xFFFF;

  __shared__ short lmem[8][8192];              // 128 KB
  short (*lA)[8192] = lmem;
  short (*lB)[8192] = lmem + 4;

  const int tid = threadIdx.x, w = tid >> 6, lane = tid & 63;

  const short* pA[2]; const short* pB[2]; int sg8[2];
  #pragma unroll
  for (int i = 0; i < 2; ++i){
    int s = (w * 2 + i) * 64 + lane;
    int r = s >> 2, j = (s & 3) ^ ((s >> 3) & 3);
    sg8[i] = s * 8;
    int p = mstart + r; if (p >= NPAIR) p = NPAIR - 1;
    pA[i] = act + (size_t)p * INTER + j * 8;
    pB[i] = w2b + ((size_t)e * HIDDEN + (size_t)ty * 256 + r) * INTER + j * 8;
  }
  auto stage = [&](int slot, int ko){
    #pragma unroll
    for (int i = 0; i < 2; ++i) gld16(pA[i] + ko, &lA[slot][sg8[i]]);
    #pragma unroll
    for (int i = 0; i < 2; ++i) gld16(pB[i] + ko, &lB[slot][sg8[i]]);
  };

  f32x4 acc[4][8];
  #pragma unroll
  for (int i = 0; i < 4; ++i)
    #pragma unroll
    for (int j = 0; j < 8; ++j) acc[i][j] = (f32x4)0.f;

  const int cc = lane & 15, ks = lane >> 4;
  const int sx = (ks ^ ((cc >> 1) & 3)) * 8;
  const int wm = w >> 1, wn = w & 1;
  int arow[4], brow[8];
  #pragma unroll
  for (int mf = 0; mf < 4; ++mf) arow[mf] = (wm * 64 + mf * 16 + cc) * 32;
  #pragma unroll
  for (int nf = 0; nf < 8; ++nf) brow[nf] = (wn * 128 + nf * 16 + cc) * 32;

  stage(0, 0); stage(1, 32); stage(2, 64); stage(3, 96);

  #pragma unroll 1
  for (int t = 0; t < 22; ++t){
    const int b = t & 1;
    // ---------- phase h=0: read slot b*2 ----------
    if (t == 0)      { WAITV(12); }
    else if (t < 21) { WAITV(8);  }
    else             { WAITV(4);  }
    SB(); BAR(); SB();
    {
      bf16x8 a0[4], bb[8];
      #pragma unroll
      for (int mf = 0; mf < 4; ++mf) a0[mf] = *(const bf16x8*)&lA[b*2][arow[mf] + sx];
      #pragma unroll
      for (int nf = 0; nf < 8; ++nf) bb[nf] = *(const bf16x8*)&lB[b*2][brow[nf] + sx];
      if (t >= 1 && t + 1 < 22) stage(((t+1)&1)*2 + 1, (t+1)*64 + 32);
      WAITL(); SB();
      __builtin_amdgcn_s_setprio(1);
      #pragma unroll
      for (int nf = 0; nf < 8; ++nf)
        #pragma unroll
        for (int mf = 0; mf < 4; ++mf)
          acc[mf][nf] = __builtin_amdgcn_mfma_f32_16x16x32_bf16(a0[mf], bb[nf], acc[mf][nf], 0, 0, 0);
      __builtin_amdgcn_s_setprio(0);
      SB(); BAR(); SB();
    }
    // ---------- phase h=1: read slot b*2+1 ----------
    if (t < 21) { WAITV(8); } else { WAITV(0); }
    SB(); BAR(); SB();
    {
      bf16x8 a0[4], bb[8];
      #pragma unroll
      for (int mf = 0; mf < 4; ++mf) a0[mf] = *(const bf16x8*)&lA[b*2+1][arow[mf] + sx];
      #pragma unroll
      for (int nf = 0; nf < 8; ++nf) bb[nf] = *(const bf16x8*)&lB[b*2+1][brow[nf] + sx];
      if (t + 2 < 22) stage(b*2, (t+2)*64);
      WAITL(); SB();
      __builtin_amdgcn_s_setprio(1);
      #pragma unroll
      for (int nf = 0; nf < 8; ++nf)
        #pragma unroll
        for (int mf = 0; mf < 4; ++mf)
          acc[mf][nf] = __builtin_amdgcn_mfma_f32_16x16x32_bf16(a0[mf], bb[nf], acc[mf][nf], 0, 0, 0);
      __builtin_amdgcn_s_setprio(0);
      SB(); BAR(); SB();
    }
  }

  // ---- epilogue: two 128-row passes through LDS [128][256] f32 (128 KB),
  // ---- then coalesced 1-KB row writes (wave w owns 16 rows per pass)
  float* lT = (float*)lmem;
  #pragma unroll 1
  for (int p = 0; p < 2; ++p){
    __syncthreads();
    if ((wm >> 1) == p){
      int rb = (wm & 1) * 64;
      #pragma unroll
      for (int mf = 0; mf < 4; ++mf){
        #pragma unroll
        for (int j = 0; j < 4; ++j){
          int prow = rb + mf * 16 + ks * 4 + j;   // 0..127
          #pragma unroll
          for (int nf = 0; nf < 8; ++nf)
            lT[prow * 256 + wn * 128 + nf * 16 + cc] = acc[mf][nf][j];
        }
      }
    }
    __syncthreads();
    #pragma unroll 1
    for (int rr = 0; rr < 16; ++rr){
      int prow = w * 16 + rr;
      int row = p * 128 + prow;
      if (row < vr){
        int ptk = pair_tk[mstart + row];
        float* orow = out + ((size_t)(ptk >> 3) * TOPK + (ptk & 7)) * HIDDEN
                      + (size_t)ty * 256;
        f32x4 v = *(const f32x4*)&lT[prow * 256 + lane * 4];
        *(f32x4*)&orow[lane * 4] = v;
      }
    }
  }
}

// ======== fallback GEMMs (in-GEMM dequant, round-1 proven) ========

__global__ __launch_bounds__(256) void k_gemm1(
    const short* __restrict__ xb,
    const float* __restrict__ w0, const float* __restrict__ s0,
    const float* __restrict__ w1, const float* __restrict__ s1,
    const int2* __restrict__ tiles, const int* __restrict__ ntiles,
    const int* __restrict__ pair_tk, short* __restrict__ act)
{
  if ((int)blockIdx.x >= *ntiles) return;
  const int2 td = tiles[blockIdx.x];
  const int mstart = td.x;
  const int e  = td.y >> 16;
  const int vr = td.y & 0xFFFF;
  const int tid = threadIdx.x;
  const int lane = tid & 63;

  __shared__ short lA[BM * 32];
  __shared__ short lB0[BM * 40];
  __shared__ short lB1[BM * 40];

  const int r0 = tid >> 2, r1 = 64 + (tid >> 2);
  const int seg = tid & 3;
  int p0 = mstart + r0; if (p0 >= NPAIR) p0 = NPAIR - 1;
  int p1 = mstart + r1; if (p1 >= NPAIR) p1 = NPAIR - 1;
  const short* arow0 = xb + (size_t)(pair_tk[p0] >> 3) * HIDDEN + (seg ^ ((r0 >> 1) & 3)) * 8;
  const short* arow1 = xb + (size_t)(pair_tk[p1] >> 3) * HIDDEN + (seg ^ ((r1 >> 1) & 3)) * 8;
  const short* ldsA0 = &lA[tid * 8];
  const short* ldsA1 = &lA[2048 + tid * 8];

  const int brow = tid >> 1, half = tid & 1;
  const int gbrow = blockIdx.y * BM + brow;
  const float* w0row = w0 + ((size_t)e * INTER + gbrow) * HIDDEN + half * 16;
  const float* w1row = w1 + ((size_t)e * INTER + gbrow) * HIDDEN + half * 16;
  const float* s0row = s0 + ((size_t)e * INTER + gbrow) * (HIDDEN / 128);
  const float* s1row = s1 + ((size_t)e * INTER + gbrow) * (HIDDEN / 128);
  short* lb0w = &lB0[brow * 40 + half * 16];
  short* lb1w = &lB1[brow * 40 + half * 16];

  f32x4 acc0[4][4], acc1[4][4];
  #pragma unroll
  for (int i = 0; i < 4; ++i)
    #pragma unroll
    for (int j = 0; j < 4; ++j){ acc0[i][j] = (f32x4)0.f; acc1[i][j] = (f32x4)0.f; }

  const int wm = tid >> 7, wn = (tid >> 6) & 1;
  const int cc = lane & 15, ks = lane >> 4;

  for (int kt = 0; kt < HIDDEN / 32; ++kt){
    gld16(arow0 + kt * 32, ldsA0);
    gld16(arow1 + kt * 32, ldsA1);
    {
      float sc = s0row[kt >> 2];
      const float* g = w0row + kt * 32;
      f32x4 q0 = *(const f32x4*)g,       q1 = *(const f32x4*)(g + 4),
            q2 = *(const f32x4*)(g + 8), q3 = *(const f32x4*)(g + 12);
      bf16x8 h0, h1;
      #pragma unroll
      for (int i = 0; i < 4; ++i){
        h0[i] = f2bf(q0[i] * sc); h0[4 + i] = f2bf(q1[i] * sc);
        h1[i] = f2bf(q2[i] * sc); h1[4 + i] = f2bf(q3[i] * sc);
      }
      *(bf16x8*)lb0w = h0; *(bf16x8*)(lb0w + 8) = h1;
    }
    {
      float sc = s1row[kt >> 2];
      const float* g = w1row + kt * 32;
      f32x4 q0 = *(const f32x4*)g,       q1 = *(const f32x4*)(g + 4),
            q2 = *(const f32x4*)(g + 8), q3 = *(const f32x4*)(g + 12);
      bf16x8 h0, h1;
      #pragma unroll
      for (int i = 0; i < 4; ++i){
        h0[i] = f2bf(q0[i] * sc); h0[4 + i] = f2bf(q1[i] * sc);
        h1[i] = f2bf(q2[i] * sc); h1[4 + i] = f2bf(q3[i] * sc);
      }
      *(bf16x8*)lb1w = h0; *(bf16x8*)(lb1w + 8) = h1;
    }
    __syncthreads();

    bf16x8 af[4];
    #pragma unroll
    for (int mf = 0; mf < 4; ++mf){
      int row = wm * 64 + mf * 16 + cc;
      af[mf] = *(const bf16x8*)&lA[row * 32 + ((ks ^ ((row >> 1) & 3)) * 8)];
    }
    #pragma unroll
    for (int nf = 0; nf < 4; ++nf){
      int rb = wn * 64 + nf * 16 + cc;
      bf16x8 b0 = *(const bf16x8*)&lB0[rb * 40 + ks * 8];
      bf16x8 b1 = *(const bf16x8*)&lB1[rb * 40 + ks * 8];
      #pragma unroll
      for (int mf = 0; mf < 4; ++mf)
        acc0[mf][nf] = __builtin_amdgcn_mfma_f32_16x16x32_bf16(af[mf], b0, acc0[mf][nf], 0, 0, 0);
      #pragma unroll
      for (int mf = 0; mf < 4; ++mf)
        acc1[mf][nf] = __builtin_amdgcn_mfma_f32_16x16x32_bf16(af[mf], b1, acc1[mf][nf], 0, 0, 0);
    }
    __syncthreads();
  }

  const int rbase = wm * 64 + (lane >> 4) * 4;
  #pragma unroll
  for (int mf = 0; mf < 4; ++mf){
    #pragma unroll
    for (int j = 0; j < 4; ++j){
      int row = rbase + mf * 16 + j;
      if (row < vr){
        short* ar = act + (size_t)(mstart + row) * INTER + blockIdx.y * BM + wn * 64 + cc;
        #pragma unroll
        for (int nf = 0; nf < 4; ++nf){
          float g = acc0[mf][nf][j], u = acc1[mf][nf][j];
          float a = g / (1.f + __expf(-g)) * u;
          ar[nf * 16] = f2bf(a);
        }
      }
    }
  }
}

__global__ __launch_bounds__(256) void k_gemm2(
    const short* __restrict__ act,
    const float* __restrict__ w2, const float* __restrict__ s2,
    const int2* __restrict__ tiles, const int* __restrict__ ntiles,
    const int* __restrict__ pair_tk, float* __restrict__ out)
{
  if ((int)blockIdx.x >= *ntiles) return;
  const int2 td = tiles[blockIdx.x];
  const int mstart = td.x;
  const int e  = td.y >> 16;
  const int vr = td.y & 0xFFFF;
  const int tid = threadIdx.x;
  const int lane = tid & 63;

  __shared__ short lA[BM * 32];
  __shared__ short lB[BM * 40];

  const int r0 = tid >> 2, r1 = 64 + (tid >> 2);
  const int seg = tid & 3;
  int p0 = mstart + r0; if (p0 >= NPAIR) p0 = NPAIR - 1;
  int p1 = mstart + r1; if (p1 >= NPAIR) p1 = NPAIR - 1;
  const short* arow0 = act + (size_t)p0 * INTER + (seg ^ ((r0 >> 1) & 3)) * 8;
  const short* arow1 = act + (size_t)p1 * INTER + (seg ^ ((r1 >> 1) & 3)) * 8;
  const short* ldsA0 = &lA[tid * 8];
  const short* ldsA1 = &lA[2048 + tid * 8];

  const int brow = tid >> 1, half = tid & 1;
  const int gbrow = blockIdx.y * BM + brow;
  const float* w2row = w2 + ((size_t)e * HIDDEN + gbrow) * INTER + half * 16;
  const float* s2row = s2 + ((size_t)e * HIDDEN + gbrow) * 11;
  short* lbw = &lB[brow * 40 + half * 16];

  f32x4 acc[4][4];
  #pragma unroll
  for (int i = 0; i < 4; ++i)
    #pragma unroll
    for (int j = 0; j < 4; ++j) acc[i][j] = (f32x4)0.f;

  const int wm = tid >> 7, wn = (tid >> 6) & 1;
  const int cc = lane & 15, ks = lane >> 4;

  for (int kt = 0; kt < INTER / 32; ++kt){
    gld16(arow0 + kt * 32, ldsA0);
    gld16(arow1 + kt * 32, ldsA1);
    {
      float sc = s2row[kt >> 2];
      const float* g = w2row + kt * 32;
      f32x4 q0 = *(const f32x4*)g,       q1 = *(const f32x4*)(g + 4),
            q2 = *(const f32x4*)(g + 8), q3 = *(const f32x4*)(g + 12);
      bf16x8 h0, h1;
      #pragma unroll
      for (int i = 0; i < 4; ++i){
        h0[i] = f2bf(q0[i] * sc); h0[4 + i] = f2bf(q1[i] * sc);
        h1[i] = f2bf(q2[i] * sc); h1[4 + i] = f2bf(q3[i] * sc);
      }
      *(bf16x8*)lbw = h0; *(bf16x8*)(lbw + 8) = h1;
    }
    __syncthreads();

    bf16x8 af[4];
    #pragma unroll
    for (int mf = 0; mf < 4; ++mf){
      int row = wm * 64 + mf * 16 + cc;
      af[mf] = *(const bf16x8*)&lA[row * 32 + ((ks ^ ((row >> 1) & 3)) * 8)];
    }
    #pragma unroll
    for (int nf = 0; nf < 4; ++nf){
      int rb = wn * 64 + nf * 16 + cc;
      bf16x8 b = *(const bf16x8*)&lB[rb * 40 + ks * 8];
      #pragma unroll
      for (int mf = 0; mf < 4; ++mf)
        acc[mf][nf] = __builtin_amdgcn_mfma_f32_16x16x32_bf16(af[mf], b, acc[mf][nf], 0, 0, 0);
    }
    __syncthreads();
  }

  const int rbase = wm * 64 + (lane >> 4) * 4;
  #pragma unroll
  for (int mf = 0; mf < 4; ++mf){
    #pragma unroll
    for (int j = 0; j < 4; ++j){
      int row = rbase + mf * 16 + j;
      if (row < vr){
        int ptk = pair_tk[mstart + row];
        float* orow = out + ((size_t)(ptk >> 3) * TOPK + (ptk & 7)) * HIDDEN
                      + blockIdx.y * BM + wn * 64 + cc;
        #pragma unroll
        for (int nf = 0; nf < 4; ++nf)
          orow[nf * 16] = acc[mf][nf][j];
      }
    }
  }
}

// ---------------- host ----------------

extern "C" void kernel_launch(void* const* d_in, const int* in_sizes, int n_in,
                              void* d_out, int out_size, void* d_ws, size_t ws_size,
                              hipStream_t stream)
{
  const float* x  = (const float*)d_in[0];
  const int*   sel= (const int*)  d_in[1];
  const float* w0 = (const float*)d_in[2];
  const float* s0 = (const float*)d_in[3];
  const float* w1 = (const float*)d_in[4];
  const float* s1 = (const float*)d_in[5];
  const float* w2 = (const float*)d_in[6];
  const float* s2 = (const float*)d_in[7];
  float* out = (float*)d_out;

  char* ws = (char*)d_ws;
  size_t o = 0;
  auto alloc = [&](size_t n){ size_t r = o; o = (o + n + 255) & ~(size_t)255; return r; };
  int*  cnt     = (int*) (ws + alloc(64));
  int*  cursor  = (int*) (ws + alloc(64));
  int*  offsets = (int*) (ws + alloc(68));
  int*  ntiles  = (int*) (ws + alloc(4));
  int*  ntiles2 = (int*) (ws + alloc(4));
  int2* tiles   = (int2*)(ws + alloc(MAXTILES * 8));
  int2* tiles2  = (int2*)(ws + alloc(MAXT2 * 8));
  int*  pair_tk = (int*) (ws + alloc((size_t)NPAIR * 4));
  short* xb     = (short*)(ws + alloc((size_t)TOKENS * HIDDEN * 2));
  short* act    = (short*)(ws + alloc((size_t)NPAIR * INTER * 2));
  const size_t WSZ = (size_t)NEXP * INTER * HIDDEN * 2;   // 92.27 MB each
  short* w0b    = (short*)(ws + alloc(WSZ));
  short* w1b    = (short*)(ws + alloc(WSZ));
  short* w2b    = (short*)(ws + alloc(WSZ));
  const bool predeq = (ws_size >= o);
  (void)in_sizes; (void)n_in; (void)out_size;

  hipMemsetAsync(ws, 0, 512, stream);   // cnt + cursor

  k_count  <<<(NPAIR + 255) / 256, 256, 0, stream>>>(sel, cnt);
  k_scan   <<<1, 64, 0, stream>>>(cnt, offsets, tiles, ntiles, tiles2, ntiles2);
  k_scatter<<<(NPAIR + 255) / 256, 256, 0, stream>>>(sel, offsets, cursor, pair_tk);

  if (predeq){
    k_deq01x<<<2 * NEXP * INTER + (TOKENS * HIDDEN) / (256 * 8), 256, 0, stream>>>(
        x, xb, w0, s0, w1, s1, w0b, w1b);
    k_g1<<<dim3(MAXT2, NT1), 512, 0, stream>>>(xb, w0b, w1b,
                                               tiles2, ntiles2, pair_tk, act);
    k_deqw2<<<2048, 256, 0, stream>>>(w2, s2, w2b);
    k_g2<<<dim3(MAXT2, NT2W), 512, 0, stream>>>(act, w2b,
                                                tiles2, ntiles2, pair_tk, out);
  } else {
    k_xcast  <<<(TOKENS * HIDDEN) / (256 * 8), 256, 0, stream>>>(x, xb);
    k_gemm1<<<dim3(MAXTILES, NT1), 256, 0, stream>>>(xb, w0, s0, w1, s1,
                                                     tiles, ntiles, pair_tk, act);
    k_gemm2<<<dim3(MAXTILES, NT2), 256, 0, stream>>>(act, w2, s2,
                                                     tiles, ntiles, pair_tk, out);
  }
}

// Round 12
// 816.484 us; speedup vs baseline: 1.0574x; 1.0078x over previous
//
#include <hip/hip_runtime.h>
#include <stdint.h>

#define TOKENS 4096
#define HIDDEN 2048
#define INTER  1408
#define NEXP   16
#define TOPK   6
#define NPAIR  (TOKENS*TOPK)          // 24576
#define BM     128
#define MAXTILES (NPAIR/BM + NEXP)    // 208 (128-row tiles, fallback path)
#define MAXT2  (NPAIR/256 + NEXP)     // 112 (256-row tiles, main path)
#define NT1    (INTER/128)            // 11
#define NT2    (HIDDEN/128)           // 16 (fallback)
#define NT2W   (HIDDEN/256)           // 8  (wide g2)

typedef __attribute__((ext_vector_type(8))) short bf16x8;
typedef __attribute__((ext_vector_type(4))) float f32x4;

__device__ __forceinline__ short f2bf(float f){
  union { float f; uint32_t u; } v; v.f = f;
  uint32_t r = (v.u + 0x7FFFu + ((v.u >> 16) & 1u)) >> 16;
  return (short)(r & 0xFFFFu);
}

__device__ __forceinline__ void gld16(const void* g, const void* l){
  __builtin_amdgcn_global_load_lds((const __attribute__((address_space(1))) void*)g,
                                   (__attribute__((address_space(3))) void*)l, 16, 0, 0);
}

__device__ __forceinline__ f32x4 ntld4(const float* p){
  return __builtin_nontemporal_load((const f32x4*)p);
}

#define SB() __builtin_amdgcn_sched_barrier(0)
#define BAR() __builtin_amdgcn_s_barrier()
#define WAITV(n) asm volatile("s_waitcnt vmcnt(" #n ")" ::: "memory")
#define WAITL() asm volatile("s_waitcnt lgkmcnt(0)" ::: "memory")

// ---------------- setup kernels ----------------

__global__ void k_xcast(const float* __restrict__ x, short* __restrict__ xb){
  int i = (blockIdx.x * 256 + threadIdx.x) * 8;
  f32x4 a = ntld4(x + i);
  f32x4 b = ntld4(x + i + 4);
  bf16x8 o;
  #pragma unroll
  for (int j = 0; j < 4; ++j){ o[j] = f2bf(a[j]); o[4+j] = f2bf(b[j]); }
  *(bf16x8*)(xb + i) = o;
}

// merged w0+w1 dequant: one row per block, nt loads on the once-read f32
__global__ void k_deq01(const float* __restrict__ w0, const float* __restrict__ s0,
                        const float* __restrict__ w1, const float* __restrict__ s1,
                        short* __restrict__ o0, short* __restrict__ o1){
  int row = blockIdx.x;
  const float* w; const float* s; short* o;
  if (row < NEXP * INTER){ w = w0; s = s0; o = o0; }
  else { row -= NEXP * INTER; w = w1; s = s1; o = o1; }
  const size_t base = (size_t)row * HIDDEN;
  const int c = threadIdx.x * 8;
  float sc = s[(size_t)row * (HIDDEN/128) + (c >> 7)];
  f32x4 a = ntld4(w + base + c);
  f32x4 b = ntld4(w + base + c + 4);
  bf16x8 h;
  #pragma unroll
  for (int j = 0; j < 4; ++j){ h[j] = f2bf(a[j] * sc); h[4+j] = f2bf(b[j] * sc); }
  *(bf16x8*)(o + base + c) = h;
}

// w2 dequant: flat grid-stride over 8-elem granules (rowlen 1408 = 176 granules)
__global__ void k_deqw2(const float* __restrict__ w2, const float* __restrict__ s2,
                        short* __restrict__ o){
  const int total = NEXP * HIDDEN * (INTER / 8);   // 5,767,168 granules
  for (int gi = blockIdx.x * 256 + threadIdx.x; gi < total; gi += gridDim.x * 256){
    int row = gi / (INTER / 8);
    int c = (gi - row * (INTER / 8)) * 8;
    const size_t base = (size_t)row * INTER;
    float sc = s2[(size_t)row * 11 + (c >> 7)];
    f32x4 a = ntld4(w2 + base + c);
    f32x4 b = ntld4(w2 + base + c + 4);
    bf16x8 h;
    #pragma unroll
    for (int j = 0; j < 4; ++j){ h[j] = f2bf(a[j] * sc); h[4+j] = f2bf(b[j] * sc); }
    *(bf16x8*)(o + base + c) = h;
  }
}

// legacy per-tensor dequant (fallback path)
__global__ void k_dequant(const float* __restrict__ w, const float* __restrict__ s,
                          short* __restrict__ o, int rowlen, int nblk){
  const int row = blockIdx.x;
  const size_t base = (size_t)row * rowlen;
  for (int c = threadIdx.x * 8; c < rowlen; c += blockDim.x * 8){
    float sc = s[(size_t)row * nblk + (c >> 7)];
    f32x4 a = *(const f32x4*)(w + base + c);
    f32x4 b = *(const f32x4*)(w + base + c + 4);
    bf16x8 h;
    #pragma unroll
    for (int j = 0; j < 4; ++j){ h[j] = f2bf(a[j] * sc); h[4+j] = f2bf(b[j] * sc); }
    *(bf16x8*)(o + base + c) = h;
  }
}

__global__ void k_count(const int* __restrict__ sel, int* __restrict__ cnt){
  int p = blockIdx.x * 256 + threadIdx.x;
  if (p < NPAIR) atomicAdd(&cnt[sel[p]], 1);
}

__global__ void k_scan(const int* __restrict__ cnt, int* __restrict__ offsets,
                       int2* __restrict__ tiles, int* __restrict__ ntiles,
                       int2* __restrict__ tiles2, int* __restrict__ ntiles2){
  if (threadIdx.x != 0) return;
  int off = 0, nt = 0, nt2 = 0;
  for (int e = 0; e < NEXP; ++e){
    offsets[e] = off;
    int c = cnt[e];
    for (int m = 0; m < c; m += BM){
      int rows = c - m; if (rows > BM) rows = BM;
      tiles[nt++] = make_int2(off + m, (e << 16) | rows);
    }
    for (int m = 0; m < c; m += 256){
      int rows = c - m; if (rows > 256) rows = 256;
      tiles2[nt2++] = make_int2(off + m, (e << 16) | rows);
    }
    off += c;
  }
  offsets[NEXP] = off;
  *ntiles = nt;
  *ntiles2 = nt2;
}

__global__ void k_scatter(const int* __restrict__ sel, const int* __restrict__ offsets,
                          int* __restrict__ cursor, int* __restrict__ pair_tk){
  int p = blockIdx.x * 256 + threadIdx.x;
  if (p >= NPAIR) return;
  int e = sel[p];
  int pos = offsets[e] + atomicAdd(&cursor[e], 1);
  pair_tk[pos] = (p / TOPK) * 8 + (p % TOPK);   // t<<3 | slot
}

// ======== main path: 256-row tiles, BK=64, 512 thr, K-half-region pipeline ========
// LDS layout [buf*2+kh][rows*32 shorts]; region contiguous so global_load_lds
// writes linearly. Granule XOR swizzle (both sides): LDS position p in row r
// holds global granule p ^ ((r>>1)&3); ds_read uses sx = (ks ^ ((cc>>1)&3))*8
// -> 2 lanes/bank = conflict-free (verified r7/r8: SQ_LDS_BANK_CONFLICT = 0).
// Schedule: phase (t,0) stages (t+1,kh1), phase (t,1) stages (t+2,kh0);
// region consumed 3 phases after issue; counted vmcnt (never 0 mid-loop).
// Epilogue: NONTEMPORAL stores (act/out never re-read within their kernel) to
// keep the B working set L3-resident (r12).

__global__ __launch_bounds__(512) void k_g1(
    const short* __restrict__ xb,
    const short* __restrict__ w0b, const short* __restrict__ w1b,
    const int2* __restrict__ tiles2, const int* __restrict__ ntiles2,
    const int* __restrict__ pair_tk, short* __restrict__ act)
{
  const int nwg = MAXT2 * NT1;                 // 1232, %8==0
  const int orig = (int)(blockIdx.y * MAXT2 + blockIdx.x);
  const int wg = (orig & 7) * (nwg >> 3) + (orig >> 3);
  const int tx = wg % MAXT2, ty = wg / MAXT2;
  if (tx >= *ntiles2) return;
  const int2 td = tiles2[tx];
  const int mstart = td.x;
  const int e  = td.y >> 16;
  const int vr = td.y & 0xFFFF;

  __shared__ short lA[4][8192];   // [buf*2+kh][256 rows * 32 shorts] = 16KB each
  __shared__ short lB[4][8192];

  const int tid = threadIdx.x, w = tid >> 6, lane = tid & 63;

  const short* pA[2]; const short* pB[2]; int sg8[2];
  #pragma unroll
  for (int i = 0; i < 2; ++i){
    int s = (w * 2 + i) * 64 + lane;
    int r = s >> 2, j = (s & 3) ^ ((s >> 3) & 3);
    sg8[i] = s * 8;
    int p = mstart + r; if (p >= NPAIR) p = NPAIR - 1;
    pA[i] = xb + (size_t)(pair_tk[p] >> 3) * HIDDEN + j * 8;
    int G = r >> 4, srow = (G >> 1) * 16 + (r & 15);
    const short* wsrc = (G & 1) ? w1b : w0b;
    pB[i] = wsrc + ((size_t)e * INTER + (size_t)ty * 128 + srow) * HIDDEN + j * 8;
  }
  auto stage = [&](int slot, int ko){     // ko = tile*64 + kh*32 (shorts)
    #pragma unroll
    for (int i = 0; i < 2; ++i) gld16(pA[i] + ko, &lA[slot][sg8[i]]);
    #pragma unroll
    for (int i = 0; i < 2; ++i) gld16(pB[i] + ko, &lB[slot][sg8[i]]);
  };

  f32x4 acc[4][8];
  #pragma unroll
  for (int i = 0; i < 4; ++i)
    #pragma unroll
    for (int j = 0; j < 8; ++j) acc[i][j] = (f32x4)0.f;

  const int cc = lane & 15, ks = lane >> 4;
  const int sx = (ks ^ ((cc >> 1) & 3)) * 8;   // swizzled read offset (shorts)
  const int wm = w >> 1, wn = w & 1;
  int arow[4], brow[8];
  #pragma unroll
  for (int mf = 0; mf < 4; ++mf) arow[mf] = (wm * 64 + mf * 16 + cc) * 32;
  #pragma unroll
  for (int nf = 0; nf < 8; ++nf) brow[nf] = (wn * 128 + nf * 16 + cc) * 32;

  stage(0, 0); stage(1, 32); stage(2, 64); stage(3, 96);

  #pragma unroll 1
  for (int t = 0; t < 32; ++t){
    const int b = t & 1;
    // ---------- phase h=0: read slot b*2 ----------
    if (t == 0)      { WAITV(12); }
    else if (t < 31) { WAITV(8);  }
    else             { WAITV(4);  }
    SB(); BAR(); SB();
    {
      bf16x8 a0[4], bb[8];
      #pragma unroll
      for (int mf = 0; mf < 4; ++mf) a0[mf] = *(const bf16x8*)&lA[b*2][arow[mf] + sx];
      #pragma unroll
      for (int nf = 0; nf < 8; ++nf) bb[nf] = *(const bf16x8*)&lB[b*2][brow[nf] + sx];
      if (t >= 1 && t + 1 < 32) stage(((t+1)&1)*2 + 1, (t+1)*64 + 32);
      WAITL(); SB();
      __builtin_amdgcn_s_setprio(1);
      #pragma unroll
      for (int nf = 0; nf < 8; ++nf)
        #pragma unroll
        for (int mf = 0; mf < 4; ++mf)
          acc[mf][nf] = __builtin_amdgcn_mfma_f32_16x16x32_bf16(a0[mf], bb[nf], acc[mf][nf], 0, 0, 0);
      __builtin_amdgcn_s_setprio(0);
      SB(); BAR(); SB();
    }
    // ---------- phase h=1: read slot b*2+1 ----------
    if (t < 31) { WAITV(8); } else { WAITV(0); }
    SB(); BAR(); SB();
    {
      bf16x8 a0[4], bb[8];
      #pragma unroll
      for (int mf = 0; mf < 4; ++mf) a0[mf] = *(const bf16x8*)&lA[b*2+1][arow[mf] + sx];
      #pragma unroll
      for (int nf = 0; nf < 8; ++nf) bb[nf] = *(const bf16x8*)&lB[b*2+1][brow[nf] + sx];
      if (t + 2 < 32) stage(b*2, (t+2)*64);
      WAITL(); SB();
      __builtin_amdgcn_s_setprio(1);
      #pragma unroll
      for (int nf = 0; nf < 8; ++nf)
        #pragma unroll
        for (int mf = 0; mf < 4; ++mf)
          acc[mf][nf] = __builtin_amdgcn_mfma_f32_16x16x32_bf16(a0[mf], bb[nf], acc[mf][nf], 0, 0, 0);
      __builtin_amdgcn_s_setprio(0);
      SB(); BAR(); SB();
    }
  }

  // epilogue: pair (gate=acc[mf][2q], up=acc[mf][2q+1]) -> act col (wn*4+q)*16+cc
  // nontemporal: act is write-once here (consumed only by k_g2 later)
  #pragma unroll
  for (int mf = 0; mf < 4; ++mf){
    #pragma unroll
    for (int j = 0; j < 4; ++j){
      int row = wm * 64 + mf * 16 + ks * 4 + j;
      if (row < vr){
        short* ar = act + (size_t)(mstart + row) * INTER + (size_t)ty * 128 + cc;
        #pragma unroll
        for (int q = 0; q < 4; ++q){
          float g = acc[mf][2*q][j], u = acc[mf][2*q+1][j];
          float a = g / (1.f + __expf(-g)) * u;
          __builtin_nontemporal_store(f2bf(a), &ar[(wn * 4 + q) * 16]);
        }
      }
    }
  }
}

// gemm2 WIDE: BN=256 (same density as g1: 32 MFMA / 12 ds_read per phase)
__global__ __launch_bounds__(512) void k_g2(
    const short* __restrict__ act, const short* __restrict__ w2b,
    const int2* __restrict__ tiles2, const int* __restrict__ ntiles2,
    const int* __restrict__ pair_tk, float* __restrict__ out)
{
  const int nwg = MAXT2 * NT2W;                // 896, %8==0
  const int orig = (int)(blockIdx.y * MAXT2 + blockIdx.x);
  const int wg = (orig & 7) * (nwg >> 3) + (orig >> 3);
  const int tx = wg % MAXT2, ty = wg / MAXT2;
  if (tx >= *ntiles2) return;
  const int2 td = tiles2[tx];
  const int mstart = td.x;
  const int e  = td.y >> 16;
  const int vr = td.y & 0xFFFF;

  __shared__ short lA[4][8192];   // 256 rows * 32
  __shared__ short lB[4][8192];   // 256 rows * 32

  const int tid = threadIdx.x, w = tid >> 6, lane = tid & 63;

  const short* pA[2]; const short* pB[2]; int sg8[2];
  #pragma unroll
  for (int i = 0; i < 2; ++i){
    int s = (w * 2 + i) * 64 + lane;
    int r = s >> 2, j = (s & 3) ^ ((s >> 3) & 3);
    sg8[i] = s * 8;
    int p = mstart + r; if (p >= NPAIR) p = NPAIR - 1;
    pA[i] = act + (size_t)p * INTER + j * 8;
    pB[i] = w2b + ((size_t)e * HIDDEN + (size_t)ty * 256 + r) * INTER + j * 8;
  }
  auto stage = [&](int slot, int ko){
    #pragma unroll
    for (int i = 0; i < 2; ++i) gld16(pA[i] + ko, &lA[slot][sg8[i]]);
    #pragma unroll
    for (int i = 0; i < 2; ++i) gld16(pB[i] + ko, &lB[slot][sg8[i]]);
  };

  f32x4 acc[4][8];
  #pragma unroll
  for (int i = 0; i < 4; ++i)
    #pragma unroll
    for (int j = 0; j < 8; ++j) acc[i][j] = (f32x4)0.f;

  const int cc = lane & 15, ks = lane >> 4;
  const int sx = (ks ^ ((cc >> 1) & 3)) * 8;
  const int wm = w >> 1, wn = w & 1;
  int arow[4], brow[8];
  #pragma unroll
  for (int mf = 0; mf < 4; ++mf) arow[mf] = (wm * 64 + mf * 16 + cc) * 32;
  #pragma unroll
  for (int nf = 0; nf < 8; ++nf) brow[nf] = (wn * 128 + nf * 16 + cc) * 32;

  stage(0, 0); stage(1, 32); stage(2, 64); stage(3, 96);

  #pragma unroll 1
  for (int t = 0; t < 22; ++t){
    const int b = t & 1;
    // ---------- phase h=0: read slot b*2 ----------
    if (t == 0)      { WAITV(12); }
    else if (t < 21) { WAITV(8);  }
    else             { WAITV(4);  }
    SB(); BAR(); SB();
    {
      bf16x8 a0[4], bb[8];
      #pragma unroll
      for (int mf = 0; mf < 4; ++mf) a0[mf] = *(const bf16x8*)&lA[b*2][arow[mf] + sx];
      #pragma unroll
      for (int nf = 0; nf < 8; ++nf) bb[nf] = *(const bf16x8*)&lB[b*2][brow[nf] + sx];
      if (t >= 1 && t + 1 < 22) stage(((t+1)&1)*2 + 1, (t+1)*64 + 32);
      WAITL(); SB();
      __builtin_amdgcn_s_setprio(1);
      #pragma unroll
      for (int nf = 0; nf < 8; ++nf)
        #pragma unroll
        for (int mf = 0; mf < 4; ++mf)
          acc[mf][nf] = __builtin_amdgcn_mfma_f32_16x16x32_bf16(a0[mf], bb[nf], acc[mf][nf], 0, 0, 0);
      __builtin_amdgcn_s_setprio(0);
      SB(); BAR(); SB();
    }
    // ---------- phase h=1: read slot b*2+1 ----------
    if (t < 21) { WAITV(8); } else { WAITV(0); }
    SB(); BAR(); SB();
    {
      bf16x8 a0[4], bb[8];
      #pragma unroll
      for (int mf = 0; mf < 4; ++mf) a0[mf] = *(const bf16x8*)&lA[b*2+1][arow[mf] + sx];
      #pragma unroll
      for (int nf = 0; nf < 8; ++nf) bb[nf] = *(const bf16x8*)&lB[b*2+1][brow[nf] + sx];
      if (t + 2 < 22) stage(b*2, (t+2)*64);
      WAITL(); SB();
      __builtin_amdgcn_s_setprio(1);
      #pragma unroll
      for (int nf = 0; nf < 8; ++nf)
        #pragma unroll
        for (int mf = 0; mf < 4; ++mf)
          acc[mf][nf] = __builtin_amdgcn_mfma_f32_16x16x32_bf16(a0[mf], bb[nf], acc[mf][nf], 0, 0, 0);
      __builtin_amdgcn_s_setprio(0);
      SB(); BAR(); SB();
    }
  }

  // epilogue: nontemporal out stores (out never re-read; keep act+w2b in L3)
  #pragma unroll
  for (int mf = 0; mf < 4; ++mf){
    #pragma unroll
    for (int j = 0; j < 4; ++j){
      int row = wm * 64 + mf * 16 + ks * 4 + j;
      if (row < vr){
        int ptk = pair_tk[mstart + row];
        float* orow = out + ((size_t)(ptk >> 3) * TOPK + (ptk & 7)) * HIDDEN
                      + (size_t)ty * 256 + wn * 128 + cc;
        #pragma unroll
        for (int nf = 0; nf < 8; ++nf)
          __builtin_nontemporal_store(acc[mf][nf][j], &orow[nf * 16]);
      }
    }
  }
}

// ======== fallback GEMMs (in-GEMM dequant, round-1 proven) ========

__global__ __launch_bounds__(256) void k_gemm1(
    const short* __restrict__ xb,
    const float* __restrict__ w0, const float* __restrict__ s0,
    const float* __restrict__ w1, const float* __restrict__ s1,
    const int2* __restrict__ tiles, const int* __restrict__ ntiles,
    const int* __restrict__ pair_tk, short* __restrict__ act)
{
  if ((int)blockIdx.x >= *ntiles) return;
  const int2 td = tiles[blockIdx.x];
  const int mstart = td.x;
  const int e  = td.y >> 16;
  const int vr = td.y & 0xFFFF;
  const int tid = threadIdx.x;
  const int lane = tid & 63;

  __shared__ short lA[BM * 32];
  __shared__ short lB0[BM * 40];
  __shared__ short lB1[BM * 40];

  const int r0 = tid >> 2, r1 = 64 + (tid >> 2);
  const int seg = tid & 3;
  int p0 = mstart + r0; if (p0 >= NPAIR) p0 = NPAIR - 1;
  int p1 = mstart + r1; if (p1 >= NPAIR) p1 = NPAIR - 1;
  const short* arow0 = xb + (size_t)(pair_tk[p0] >> 3) * HIDDEN + (seg ^ ((r0 >> 1) & 3)) * 8;
  const short* arow1 = xb + (size_t)(pair_tk[p1] >> 3) * HIDDEN + (seg ^ ((r1 >> 1) & 3)) * 8;
  const short* ldsA0 = &lA[tid * 8];
  const short* ldsA1 = &lA[2048 + tid * 8];

  const int brow = tid >> 1, half = tid & 1;
  const int gbrow = blockIdx.y * BM + brow;
  const float* w0row = w0 + ((size_t)e * INTER + gbrow) * HIDDEN + half * 16;
  const float* w1row = w1 + ((size_t)e * INTER + gbrow) * HIDDEN + half * 16;
  const float* s0row = s0 + ((size_t)e * INTER + gbrow) * (HIDDEN / 128);
  const float* s1row = s1 + ((size_t)e * INTER + gbrow) * (HIDDEN / 128);
  short* lb0w = &lB0[brow * 40 + half * 16];
  short* lb1w = &lB1[brow * 40 + half * 16];

  f32x4 acc0[4][4], acc1[4][4];
  #pragma unroll
  for (int i = 0; i < 4; ++i)
    #pragma unroll
    for (int j = 0; j < 4; ++j){ acc0[i][j] = (f32x4)0.f; acc1[i][j] = (f32x4)0.f; }

  const int wm = tid >> 7, wn = (tid >> 6) & 1;
  const int cc = lane & 15, ks = lane >> 4;

  for (int kt = 0; kt < HIDDEN / 32; ++kt){
    gld16(arow0 + kt * 32, ldsA0);
    gld16(arow1 + kt * 32, ldsA1);
    {
      float sc = s0row[kt >> 2];
      const float* g = w0row + kt * 32;
      f32x4 q0 = *(const f32x4*)g,       q1 = *(const f32x4*)(g + 4),
            q2 = *(const f32x4*)(g + 8), q3 = *(const f32x4*)(g + 12);
      bf16x8 h0, h1;
      #pragma unroll
      for (int i = 0; i < 4; ++i){
        h0[i] = f2bf(q0[i] * sc); h0[4 + i] = f2bf(q1[i] * sc);
        h1[i] = f2bf(q2[i] * sc); h1[4 + i] = f2bf(q3[i] * sc);
      }
      *(bf16x8*)lb0w = h0; *(bf16x8*)(lb0w + 8) = h1;
    }
    {
      float sc = s1row[kt >> 2];
      const float* g = w1row + kt * 32;
      f32x4 q0 = *(const f32x4*)g,       q1 = *(const f32x4*)(g + 4),
            q2 = *(const f32x4*)(g + 8), q3 = *(const f32x4*)(g + 12);
      bf16x8 h0, h1;
      #pragma unroll
      for (int i = 0; i < 4; ++i){
        h0[i] = f2bf(q0[i] * sc); h0[4 + i] = f2bf(q1[i] * sc);
        h1[i] = f2bf(q2[i] * sc); h1[4 + i] = f2bf(q3[i] * sc);
      }
      *(bf16x8*)lb1w = h0; *(bf16x8*)(lb1w + 8) = h1;
    }
    __syncthreads();

    bf16x8 af[4];
    #pragma unroll
    for (int mf = 0; mf < 4; ++mf){
      int row = wm * 64 + mf * 16 + cc;
      af[mf] = *(const bf16x8*)&lA[row * 32 + ((ks ^ ((row >> 1) & 3)) * 8)];
    }
    #pragma unroll
    for (int nf = 0; nf < 4; ++nf){
      int rb = wn * 64 + nf * 16 + cc;
      bf16x8 b0 = *(const bf16x8*)&lB0[rb * 40 + ks * 8];
      bf16x8 b1 = *(const bf16x8*)&lB1[rb * 40 + ks * 8];
      #pragma unroll
      for (int mf = 0; mf < 4; ++mf)
        acc0[mf][nf] = __builtin_amdgcn_mfma_f32_16x16x32_bf16(af[mf], b0, acc0[mf][nf], 0, 0, 0);
      #pragma unroll
      for (int mf = 0; mf < 4; ++mf)
        acc1[mf][nf] = __builtin_amdgcn_mfma_f32_16x16x32_bf16(af[mf], b1, acc1[mf][nf], 0, 0, 0);
    }
    __syncthreads();
  }

  const int rbase = wm * 64 + (lane >> 4) * 4;
  #pragma unroll
  for (int mf = 0; mf < 4; ++mf){
    #pragma unroll
    for (int j = 0; j < 4; ++j){
      int row = rbase + mf * 16 + j;
      if (row < vr){
        short* ar = act + (size_t)(mstart + row) * INTER + blockIdx.y * BM + wn * 64 + cc;
        #pragma unroll
        for (int nf = 0; nf < 4; ++nf){
          float g = acc0[mf][nf][j], u = acc1[mf][nf][j];
          float a = g / (1.f + __expf(-g)) * u;
          ar[nf * 16] = f2bf(a);
        }
      }
    }
  }
}

__global__ __launch_bounds__(256) void k_gemm2(
    const short* __restrict__ act,
    const float* __restrict__ w2, const float* __restrict__ s2,
    const int2* __restrict__ tiles, const int* __restrict__ ntiles,
    const int* __restrict__ pair_tk, float* __restrict__ out)
{
  if ((int)blockIdx.x >= *ntiles) return;
  const int2 td = tiles[blockIdx.x];
  const int mstart = td.x;
  const int e  = td.y >> 16;
  const int vr = td.y & 0xFFFF;
  const int tid = threadIdx.x;
  const int lane = tid & 63;

  __shared__ short lA[BM * 32];
  __shared__ short lB[BM * 40];

  const int r0 = tid >> 2, r1 = 64 + (tid >> 2);
  const int seg = tid & 3;
  int p0 = mstart + r0; if (p0 >= NPAIR) p0 = NPAIR - 1;
  int p1 = mstart + r1; if (p1 >= NPAIR) p1 = NPAIR - 1;
  const short* arow0 = act + (size_t)p0 * INTER + (seg ^ ((r0 >> 1) & 3)) * 8;
  const short* arow1 = act + (size_t)p1 * INTER + (seg ^ ((r1 >> 1) & 3)) * 8;
  const short* ldsA0 = &lA[tid * 8];
  const short* ldsA1 = &lA[2048 + tid * 8];

  const int brow = tid >> 1, half = tid & 1;
  const int gbrow = blockIdx.y * BM + brow;
  const float* w2row = w2 + ((size_t)e * HIDDEN + gbrow) * INTER + half * 16;
  const float* s2row = s2 + ((size_t)e * HIDDEN + gbrow) * 11;
  short* lbw = &lB[brow * 40 + half * 16];

  f32x4 acc[4][4];
  #pragma unroll
  for (int i = 0; i < 4; ++i)
    #pragma unroll
    for (int j = 0; j < 4; ++j) acc[i][j] = (f32x4)0.f;

  const int wm = tid >> 7, wn = (tid >> 6) & 1;
  const int cc = lane & 15, ks = lane >> 4;

  for (int kt = 0; kt < INTER / 32; ++kt){
    gld16(arow0 + kt * 32, ldsA0);
    gld16(arow1 + kt * 32, ldsA1);
    {
      float sc = s2row[kt >> 2];
      const float* g = w2row + kt * 32;
      f32x4 q0 = *(const f32x4*)g,       q1 = *(const f32x4*)(g + 4),
            q2 = *(const f32x4*)(g + 8), q3 = *(const f32x4*)(g + 12);
      bf16x8 h0, h1;
      #pragma unroll
      for (int i = 0; i < 4; ++i){
        h0[i] = f2bf(q0[i] * sc); h0[4 + i] = f2bf(q1[i] * sc);
        h1[i] = f2bf(q2[i] * sc); h1[4 + i] = f2bf(q3[i] * sc);
      }
      *(bf16x8*)lbw = h0; *(bf16x8*)(lbw + 8) = h1;
    }
    __syncthreads();

    bf16x8 af[4];
    #pragma unroll
    for (int mf = 0; mf < 4; ++mf){
      int row = wm * 64 + mf * 16 + cc;
      af[mf] = *(const bf16x8*)&lA[row * 32 + ((ks ^ ((row >> 1) & 3)) * 8)];
    }
    #pragma unroll
    for (int nf = 0; nf < 4; ++nf){
      int rb = wn * 64 + nf * 16 + cc;
      bf16x8 b = *(const bf16x8*)&lB[rb * 40 + ks * 8];
      #pragma unroll
      for (int mf = 0; mf < 4; ++mf)
        acc[mf][nf] = __builtin_amdgcn_mfma_f32_16x16x32_bf16(af[mf], b, acc[mf][nf], 0, 0, 0);
    }
    __syncthreads();
  }

  const int rbase = wm * 64 + (lane >> 4) * 4;
  #pragma unroll
  for (int mf = 0; mf < 4; ++mf){
    #pragma unroll
    for (int j = 0; j < 4; ++j){
      int row = rbase + mf * 16 + j;
      if (row < vr){
        int ptk = pair_tk[mstart + row];
        float* orow = out + ((size_t)(ptk >> 3) * TOPK + (ptk & 7)) * HIDDEN
                      + blockIdx.y * BM + wn * 64 + cc;
        #pragma unroll
        for (int nf = 0; nf < 4; ++nf)
          orow[nf * 16] = acc[mf][nf][j];
      }
    }
  }
}

// ---------------- host ----------------

extern "C" void kernel_launch(void* const* d_in, const int* in_sizes, int n_in,
                              void* d_out, int out_size, void* d_ws, size_t ws_size,
                              hipStream_t stream)
{
  const float* x  = (const float*)d_in[0];
  const int*   sel= (const int*)  d_in[1];
  const float* w0 = (const float*)d_in[2];
  const float* s0 = (const float*)d_in[3];
  const float* w1 = (const float*)d_in[4];
  const float* s1 = (const float*)d_in[5];
  const float* w2 = (const float*)d_in[6];
  const float* s2 = (const float*)d_in[7];
  float* out = (float*)d_out;

  char* ws = (char*)d_ws;
  size_t o = 0;
  auto alloc = [&](size_t n){ size_t r = o; o = (o + n + 255) & ~(size_t)255; return r; };
  int*  cnt     = (int*) (ws + alloc(64));
  int*  cursor  = (int*) (ws + alloc(64));
  int*  offsets = (int*) (ws + alloc(68));
  int*  ntiles  = (int*) (ws + alloc(4));
  int*  ntiles2 = (int*) (ws + alloc(4));
  int2* tiles   = (int2*)(ws + alloc(MAXTILES * 8));
  int2* tiles2  = (int2*)(ws + alloc(MAXT2 * 8));
  int*  pair_tk = (int*) (ws + alloc((size_t)NPAIR * 4));
  short* xb     = (short*)(ws + alloc((size_t)TOKENS * HIDDEN * 2));
  short* act    = (short*)(ws + alloc((size_t)NPAIR * INTER * 2));
  const size_t WSZ = (size_t)NEXP * INTER * HIDDEN * 2;   // 92.27 MB each
  short* w0b    = (short*)(ws + alloc(WSZ));
  short* w1b    = (short*)(ws + alloc(WSZ));
  short* w2b    = (short*)(ws + alloc(WSZ));
  const bool predeq = (ws_size >= o);
  (void)in_sizes; (void)n_in; (void)out_size;

  hipMemsetAsync(ws, 0, 512, stream);   // cnt + cursor

  k_xcast  <<<(TOKENS * HIDDEN) / (256 * 8), 256, 0, stream>>>(x, xb);
  k_count  <<<(NPAIR + 255) / 256, 256, 0, stream>>>(sel, cnt);
  k_scan   <<<1, 64, 0, stream>>>(cnt, offsets, tiles, ntiles, tiles2, ntiles2);
  k_scatter<<<(NPAIR + 255) / 256, 256, 0, stream>>>(sel, offsets, cursor, pair_tk);

  if (predeq){
    // dequant w0+w1 merged; w2 AFTER g1 so it doesn't thrash L3 during g1
    k_deq01<<<2 * NEXP * INTER, 256, 0, stream>>>(w0, s0, w1, s1, w0b, w1b);
    k_g1<<<dim3(MAXT2, NT1), 512, 0, stream>>>(xb, w0b, w1b,
                                               tiles2, ntiles2, pair_tk, act);
    k_deqw2<<<2048, 256, 0, stream>>>(w2, s2, w2b);
    k_g2<<<dim3(MAXT2, NT2W), 512, 0, stream>>>(act, w2b,
                                                tiles2, ntiles2, pair_tk, out);
  } else {
    k_gemm1<<<dim3(MAXTILES, NT1), 256, 0, stream>>>(xb, w0, s0, w1, s1,
                                                     tiles, ntiles, pair_tk, act);
    k_gemm2<<<dim3(MAXTILES, NT2), 256, 0, stream>>>(act, w2, s2,
                                                     tiles, ntiles, pair_tk, out);
  }
}

// Round 13
// 804.486 us; speedup vs baseline: 1.0731x; 1.0149x over previous
//
#include <hip/hip_runtime.h>
#include <stdint.h>

#define TOKENS 4096
#define HIDDEN 2048
#define INTER  1408
#define NEXP   16
#define TOPK   6
#define NPAIR  (TOKENS*TOPK)          // 24576
#define BM     128
#define MAXTILES (NPAIR/BM + NEXP)    // 208 (128-row tiles, fallback path)
#define MAXT2  (NPAIR/256 + NEXP)     // 112 (256-row tiles, main path)
#define NT1    (INTER/128)            // 11
#define NT2    (HIDDEN/128)           // 16 (fallback)
#define NT2W   (HIDDEN/256)           // 8  (wide g2)

typedef __attribute__((ext_vector_type(8))) short bf16x8;
typedef __attribute__((ext_vector_type(4))) float f32x4;

__device__ __forceinline__ short f2bf(float f){
  union { float f; uint32_t u; } v; v.f = f;
  uint32_t r = (v.u + 0x7FFFu + ((v.u >> 16) & 1u)) >> 16;
  return (short)(r & 0xFFFFu);
}

__device__ __forceinline__ void gld16(const void* g, const void* l){
  __builtin_amdgcn_global_load_lds((const __attribute__((address_space(1))) void*)g,
                                   (__attribute__((address_space(3))) void*)l, 16, 0, 0);
}

__device__ __forceinline__ f32x4 ntld4(const float* p){
  return __builtin_nontemporal_load((const f32x4*)p);
}

#define SB() __builtin_amdgcn_sched_barrier(0)
#define BAR() __builtin_amdgcn_s_barrier()
#define WAITV(n) asm volatile("s_waitcnt vmcnt(" #n ")" ::: "memory")
#define WAITL() asm volatile("s_waitcnt lgkmcnt(0)" ::: "memory")

// ---------------- setup kernels ----------------

__global__ void k_xcast(const float* __restrict__ x, short* __restrict__ xb){
  int i = (blockIdx.x * 256 + threadIdx.x) * 8;
  f32x4 a = ntld4(x + i);
  f32x4 b = ntld4(x + i + 4);
  bf16x8 o;
  #pragma unroll
  for (int j = 0; j < 4; ++j){ o[j] = f2bf(a[j]); o[4+j] = f2bf(b[j]); }
  *(bf16x8*)(xb + i) = o;
}

// merged w0+w1 dequant: one row per block, nt loads on the once-read f32
__global__ void k_deq01(const float* __restrict__ w0, const float* __restrict__ s0,
                        const float* __restrict__ w1, const float* __restrict__ s1,
                        short* __restrict__ o0, short* __restrict__ o1){
  int row = blockIdx.x;
  const float* w; const float* s; short* o;
  if (row < NEXP * INTER){ w = w0; s = s0; o = o0; }
  else { row -= NEXP * INTER; w = w1; s = s1; o = o1; }
  const size_t base = (size_t)row * HIDDEN;
  const int c = threadIdx.x * 8;
  float sc = s[(size_t)row * (HIDDEN/128) + (c >> 7)];
  f32x4 a = ntld4(w + base + c);
  f32x4 b = ntld4(w + base + c + 4);
  bf16x8 h;
  #pragma unroll
  for (int j = 0; j < 4; ++j){ h[j] = f2bf(a[j] * sc); h[4+j] = f2bf(b[j] * sc); }
  *(bf16x8*)(o + base + c) = h;
}

// w2 dequant: flat grid-stride over 8-elem granules (rowlen 1408 = 176 granules)
__global__ void k_deqw2(const float* __restrict__ w2, const float* __restrict__ s2,
                        short* __restrict__ o){
  const int total = NEXP * HIDDEN * (INTER / 8);   // 5,767,168 granules
  for (int gi = blockIdx.x * 256 + threadIdx.x; gi < total; gi += gridDim.x * 256){
    int row = gi / (INTER / 8);
    int c = (gi - row * (INTER / 8)) * 8;
    const size_t base = (size_t)row * INTER;
    float sc = s2[(size_t)row * 11 + (c >> 7)];
    f32x4 a = ntld4(w2 + base + c);
    f32x4 b = ntld4(w2 + base + c + 4);
    bf16x8 h;
    #pragma unroll
    for (int j = 0; j < 4; ++j){ h[j] = f2bf(a[j] * sc); h[4+j] = f2bf(b[j] * sc); }
    *(bf16x8*)(o + base + c) = h;
  }
}

// legacy per-tensor dequant (fallback path)
__global__ void k_dequant(const float* __restrict__ w, const float* __restrict__ s,
                          short* __restrict__ o, int rowlen, int nblk){
  const int row = blockIdx.x;
  const size_t base = (size_t)row * rowlen;
  for (int c = threadIdx.x * 8; c < rowlen; c += blockDim.x * 8){
    float sc = s[(size_t)row * nblk + (c >> 7)];
    f32x4 a = *(const f32x4*)(w + base + c);
    f32x4 b = *(const f32x4*)(w + base + c + 4);
    bf16x8 h;
    #pragma unroll
    for (int j = 0; j < 4; ++j){ h[j] = f2bf(a[j] * sc); h[4+j] = f2bf(b[j] * sc); }
    *(bf16x8*)(o + base + c) = h;
  }
}

__global__ void k_count(const int* __restrict__ sel, int* __restrict__ cnt){
  int p = blockIdx.x * 256 + threadIdx.x;
  if (p < NPAIR) atomicAdd(&cnt[sel[p]], 1);
}

__global__ void k_scan(const int* __restrict__ cnt, int* __restrict__ offsets,
                       int2* __restrict__ tiles, int* __restrict__ ntiles,
                       int2* __restrict__ tiles2, int* __restrict__ ntiles2){
  if (threadIdx.x != 0) return;
  int off = 0, nt = 0, nt2 = 0;
  for (int e = 0; e < NEXP; ++e){
    offsets[e] = off;
    int c = cnt[e];
    for (int m = 0; m < c; m += BM){
      int rows = c - m; if (rows > BM) rows = BM;
      tiles[nt++] = make_int2(off + m, (e << 16) | rows);
    }
    for (int m = 0; m < c; m += 256){
      int rows = c - m; if (rows > 256) rows = 256;
      tiles2[nt2++] = make_int2(off + m, (e << 16) | rows);
    }
    off += c;
  }
  offsets[NEXP] = off;
  *ntiles = nt;
  *ntiles2 = nt2;
}

__global__ void k_scatter(const int* __restrict__ sel, const int* __restrict__ offsets,
                          int* __restrict__ cursor, int* __restrict__ pair_tk){
  int p = blockIdx.x * 256 + threadIdx.x;
  if (p >= NPAIR) return;
  int e = sel[p];
  int pos = offsets[e] + atomicAdd(&cursor[e], 1);
  pair_tk[pos] = (p / TOPK) * 8 + (p % TOPK);   // t<<3 | slot
}

// ======== main path: 256-row tiles, BK=64, 512 thr, K-half-region pipeline ========
// LDS layout [slot][rows*32 shorts], slot(t,h) = (t&1)*2+h; region contiguous so
// global_load_lds writes linearly. Granule XOR swizzle (both sides): LDS pos p in
// row r holds global granule p ^ ((r>>1)&3); ds_read sx = (ks ^ ((cc>>1)&3))*8 ->
// 2 lanes/bank = conflict-free (verified r7/r8: SQ_LDS_BANK_CONFLICT = 0).
// r13 schedule: ONE barrier per phase (the redundant post-MFMA barrier removed —
// readers retire ds_reads via lgkmcnt(0) before MFMA, hence before the NEXT
// phase's barrier; restage of a slot happens 2 phases after its last read).
// Phase (t,h): WAITV(4); BAR; ds_reads(slot(t,h)); stage region (t+1,h);
// lgkmcnt(0); 32 MFMA. Uniform vmcnt(4) = exactly one region in flight.

__global__ __launch_bounds__(512) void k_g1(
    const short* __restrict__ xb,
    const short* __restrict__ w0b, const short* __restrict__ w1b,
    const int2* __restrict__ tiles2, const int* __restrict__ ntiles2,
    const int* __restrict__ pair_tk, short* __restrict__ act)
{
  const int nwg = MAXT2 * NT1;                 // 1232, %8==0
  const int orig = (int)(blockIdx.y * MAXT2 + blockIdx.x);
  const int wg = (orig & 7) * (nwg >> 3) + (orig >> 3);
  const int tx = wg % MAXT2, ty = wg / MAXT2;
  if (tx >= *ntiles2) return;
  const int2 td = tiles2[tx];
  const int mstart = td.x;
  const int e  = td.y >> 16;
  const int vr = td.y & 0xFFFF;

  __shared__ short lA[4][8192];   // [slot][256 rows * 32 shorts] = 16KB each
  __shared__ short lB[4][8192];

  const int tid = threadIdx.x, w = tid >> 6, lane = tid & 63;

  const short* pA[2]; const short* pB[2]; int sg8[2];
  #pragma unroll
  for (int i = 0; i < 2; ++i){
    int s = (w * 2 + i) * 64 + lane;
    int r = s >> 2, j = (s & 3) ^ ((s >> 3) & 3);
    sg8[i] = s * 8;
    int p = mstart + r; if (p >= NPAIR) p = NPAIR - 1;
    pA[i] = xb + (size_t)(pair_tk[p] >> 3) * HIDDEN + j * 8;
    int G = r >> 4, srow = (G >> 1) * 16 + (r & 15);
    const short* wsrc = (G & 1) ? w1b : w0b;
    pB[i] = wsrc + ((size_t)e * INTER + (size_t)ty * 128 + srow) * HIDDEN + j * 8;
  }
  auto stage = [&](int slot, int ko){     // ko = tile*64 + kh*32 (shorts); 4 gld/thread
    #pragma unroll
    for (int i = 0; i < 2; ++i) gld16(pA[i] + ko, &lA[slot][sg8[i]]);
    #pragma unroll
    for (int i = 0; i < 2; ++i) gld16(pB[i] + ko, &lB[slot][sg8[i]]);
  };

  f32x4 acc[4][8];
  #pragma unroll
  for (int i = 0; i < 4; ++i)
    #pragma unroll
    for (int j = 0; j < 8; ++j) acc[i][j] = (f32x4)0.f;

  const int cc = lane & 15, ks = lane >> 4;
  const int sx = (ks ^ ((cc >> 1) & 3)) * 8;   // swizzled read offset (shorts)
  const int wm = w >> 1, wn = w & 1;
  int arow[4], brow[8];
  #pragma unroll
  for (int mf = 0; mf < 4; ++mf) arow[mf] = (wm * 64 + mf * 16 + cc) * 32;
  #pragma unroll
  for (int nf = 0; nf < 8; ++nf) brow[nf] = (wn * 128 + nf * 16 + cc) * 32;

  // prologue: regions (0,0),(0,1) -> slots 0,1
  stage(0, 0); stage(1, 32);

  #pragma unroll 1
  for (int t = 0; t < 32; ++t){
    #pragma unroll
    for (int h = 0; h < 2; ++h){
      if (t == 31 && h == 1) { WAITV(0); } else { WAITV(4); }
      SB(); BAR(); SB();
      const short* A = lA[(t & 1) * 2 + h];
      const short* B = lB[(t & 1) * 2 + h];
      bf16x8 a0[4], bb[8];
      #pragma unroll
      for (int mf = 0; mf < 4; ++mf) a0[mf] = *(const bf16x8*)&A[arow[mf] + sx];
      #pragma unroll
      for (int nf = 0; nf < 8; ++nf) bb[nf] = *(const bf16x8*)&B[brow[nf] + sx];
      if (t + 1 < 32) stage(((t + 1) & 1) * 2 + h, (t + 1) * 64 + h * 32);
      WAITL(); SB();
      __builtin_amdgcn_s_setprio(1);
      #pragma unroll
      for (int nf = 0; nf < 8; ++nf)
        #pragma unroll
        for (int mf = 0; mf < 4; ++mf)
          acc[mf][nf] = __builtin_amdgcn_mfma_f32_16x16x32_bf16(a0[mf], bb[nf], acc[mf][nf], 0, 0, 0);
      __builtin_amdgcn_s_setprio(0);
      SB();
    }
  }

  // epilogue: pair (gate=acc[mf][2q], up=acc[mf][2q+1]) -> act col (wn*4+q)*16+cc
  // nontemporal: act is write-once here (consumed only by k_g2 later)
  #pragma unroll
  for (int mf = 0; mf < 4; ++mf){
    #pragma unroll
    for (int j = 0; j < 4; ++j){
      int row = wm * 64 + mf * 16 + ks * 4 + j;
      if (row < vr){
        short* ar = act + (size_t)(mstart + row) * INTER + (size_t)ty * 128 + cc;
        #pragma unroll
        for (int q = 0; q < 4; ++q){
          float g = acc[mf][2*q][j], u = acc[mf][2*q+1][j];
          float a = g / (1.f + __expf(-g)) * u;
          __builtin_nontemporal_store(f2bf(a), &ar[(wn * 4 + q) * 16]);
        }
      }
    }
  }
}

// gemm2 WIDE: BN=256, same r13 single-barrier schedule
__global__ __launch_bounds__(512) void k_g2(
    const short* __restrict__ act, const short* __restrict__ w2b,
    const int2* __restrict__ tiles2, const int* __restrict__ ntiles2,
    const int* __restrict__ pair_tk, float* __restrict__ out)
{
  const int nwg = MAXT2 * NT2W;                // 896, %8==0
  const int orig = (int)(blockIdx.y * MAXT2 + blockIdx.x);
  const int wg = (orig & 7) * (nwg >> 3) + (orig >> 3);
  const int tx = wg % MAXT2, ty = wg / MAXT2;
  if (tx >= *ntiles2) return;
  const int2 td = tiles2[tx];
  const int mstart = td.x;
  const int e  = td.y >> 16;
  const int vr = td.y & 0xFFFF;

  __shared__ short lA[4][8192];   // 256 rows * 32
  __shared__ short lB[4][8192];   // 256 rows * 32

  const int tid = threadIdx.x, w = tid >> 6, lane = tid & 63;

  const short* pA[2]; const short* pB[2]; int sg8[2];
  #pragma unroll
  for (int i = 0; i < 2; ++i){
    int s = (w * 2 + i) * 64 + lane;
    int r = s >> 2, j = (s & 3) ^ ((s >> 3) & 3);
    sg8[i] = s * 8;
    int p = mstart + r; if (p >= NPAIR) p = NPAIR - 1;
    pA[i] = act + (size_t)p * INTER + j * 8;
    pB[i] = w2b + ((size_t)e * HIDDEN + (size_t)ty * 256 + r) * INTER + j * 8;
  }
  auto stage = [&](int slot, int ko){
    #pragma unroll
    for (int i = 0; i < 2; ++i) gld16(pA[i] + ko, &lA[slot][sg8[i]]);
    #pragma unroll
    for (int i = 0; i < 2; ++i) gld16(pB[i] + ko, &lB[slot][sg8[i]]);
  };

  f32x4 acc[4][8];
  #pragma unroll
  for (int i = 0; i < 4; ++i)
    #pragma unroll
    for (int j = 0; j < 8; ++j) acc[i][j] = (f32x4)0.f;

  const int cc = lane & 15, ks = lane >> 4;
  const int sx = (ks ^ ((cc >> 1) & 3)) * 8;
  const int wm = w >> 1, wn = w & 1;
  int arow[4], brow[8];
  #pragma unroll
  for (int mf = 0; mf < 4; ++mf) arow[mf] = (wm * 64 + mf * 16 + cc) * 32;
  #pragma unroll
  for (int nf = 0; nf < 8; ++nf) brow[nf] = (wn * 128 + nf * 16 + cc) * 32;

  stage(0, 0); stage(1, 32);

  #pragma unroll 1
  for (int t = 0; t < 22; ++t){
    #pragma unroll
    for (int h = 0; h < 2; ++h){
      if (t == 21 && h == 1) { WAITV(0); } else { WAITV(4); }
      SB(); BAR(); SB();
      const short* A = lA[(t & 1) * 2 + h];
      const short* B = lB[(t & 1) * 2 + h];
      bf16x8 a0[4], bb[8];
      #pragma unroll
      for (int mf = 0; mf < 4; ++mf) a0[mf] = *(const bf16x8*)&A[arow[mf] + sx];
      #pragma unroll
      for (int nf = 0; nf < 8; ++nf) bb[nf] = *(const bf16x8*)&B[brow[nf] + sx];
      if (t + 1 < 22) stage(((t + 1) & 1) * 2 + h, (t + 1) * 64 + h * 32);
      WAITL(); SB();
      __builtin_amdgcn_s_setprio(1);
      #pragma unroll
      for (int nf = 0; nf < 8; ++nf)
        #pragma unroll
        for (int mf = 0; mf < 4; ++mf)
          acc[mf][nf] = __builtin_amdgcn_mfma_f32_16x16x32_bf16(a0[mf], bb[nf], acc[mf][nf], 0, 0, 0);
      __builtin_amdgcn_s_setprio(0);
      SB();
    }
  }

  // epilogue: nontemporal out stores (out never re-read; keep act+w2b in L3)
  #pragma unroll
  for (int mf = 0; mf < 4; ++mf){
    #pragma unroll
    for (int j = 0; j < 4; ++j){
      int row = wm * 64 + mf * 16 + ks * 4 + j;
      if (row < vr){
        int ptk = pair_tk[mstart + row];
        float* orow = out + ((size_t)(ptk >> 3) * TOPK + (ptk & 7)) * HIDDEN
                      + (size_t)ty * 256 + wn * 128 + cc;
        #pragma unroll
        for (int nf = 0; nf < 8; ++nf)
          __builtin_nontemporal_store(acc[mf][nf][j], &orow[nf * 16]);
      }
    }
  }
}

// ======== fallback GEMMs (in-GEMM dequant, round-1 proven) ========

__global__ __launch_bounds__(256) void k_gemm1(
    const short* __restrict__ xb,
    const float* __restrict__ w0, const float* __restrict__ s0,
    const float* __restrict__ w1, const float* __restrict__ s1,
    const int2* __restrict__ tiles, const int* __restrict__ ntiles,
    const int* __restrict__ pair_tk, short* __restrict__ act)
{
  if ((int)blockIdx.x >= *ntiles) return;
  const int2 td = tiles[blockIdx.x];
  const int mstart = td.x;
  const int e  = td.y >> 16;
  const int vr = td.y & 0xFFFF;
  const int tid = threadIdx.x;
  const int lane = tid & 63;

  __shared__ short lA[BM * 32];
  __shared__ short lB0[BM * 40];
  __shared__ short lB1[BM * 40];

  const int r0 = tid >> 2, r1 = 64 + (tid >> 2);
  const int seg = tid & 3;
  int p0 = mstart + r0; if (p0 >= NPAIR) p0 = NPAIR - 1;
  int p1 = mstart + r1; if (p1 >= NPAIR) p1 = NPAIR - 1;
  const short* arow0 = xb + (size_t)(pair_tk[p0] >> 3) * HIDDEN + (seg ^ ((r0 >> 1) & 3)) * 8;
  const short* arow1 = xb + (size_t)(pair_tk[p1] >> 3) * HIDDEN + (seg ^ ((r1 >> 1) & 3)) * 8;
  const short* ldsA0 = &lA[tid * 8];
  const short* ldsA1 = &lA[2048 + tid * 8];

  const int brow = tid >> 1, half = tid & 1;
  const int gbrow = blockIdx.y * BM + brow;
  const float* w0row = w0 + ((size_t)e * INTER + gbrow) * HIDDEN + half * 16;
  const float* w1row = w1 + ((size_t)e * INTER + gbrow) * HIDDEN + half * 16;
  const float* s0row = s0 + ((size_t)e * INTER + gbrow) * (HIDDEN / 128);
  const float* s1row = s1 + ((size_t)e * INTER + gbrow) * (HIDDEN / 128);
  short* lb0w = &lB0[brow * 40 + half * 16];
  short* lb1w = &lB1[brow * 40 + half * 16];

  f32x4 acc0[4][4], acc1[4][4];
  #pragma unroll
  for (int i = 0; i < 4; ++i)
    #pragma unroll
    for (int j = 0; j < 4; ++j){ acc0[i][j] = (f32x4)0.f; acc1[i][j] = (f32x4)0.f; }

  const int wm = tid >> 7, wn = (tid >> 6) & 1;
  const int cc = lane & 15, ks = lane >> 4;

  for (int kt = 0; kt < HIDDEN / 32; ++kt){
    gld16(arow0 + kt * 32, ldsA0);
    gld16(arow1 + kt * 32, ldsA1);
    {
      float sc = s0row[kt >> 2];
      const float* g = w0row + kt * 32;
      f32x4 q0 = *(const f32x4*)g,       q1 = *(const f32x4*)(g + 4),
            q2 = *(const f32x4*)(g + 8), q3 = *(const f32x4*)(g + 12);
      bf16x8 h0, h1;
      #pragma unroll
      for (int i = 0; i < 4; ++i){
        h0[i] = f2bf(q0[i] * sc); h0[4 + i] = f2bf(q1[i] * sc);
        h1[i] = f2bf(q2[i] * sc); h1[4 + i] = f2bf(q3[i] * sc);
      }
      *(bf16x8*)lb0w = h0; *(bf16x8*)(lb0w + 8) = h1;
    }
    {
      float sc = s1row[kt >> 2];
      const float* g = w1row + kt * 32;
      f32x4 q0 = *(const f32x4*)g,       q1 = *(const f32x4*)(g + 4),
            q2 = *(const f32x4*)(g + 8), q3 = *(const f32x4*)(g + 12);
      bf16x8 h0, h1;
      #pragma unroll
      for (int i = 0; i < 4; ++i){
        h0[i] = f2bf(q0[i] * sc); h0[4 + i] = f2bf(q1[i] * sc);
        h1[i] = f2bf(q2[i] * sc); h1[4 + i] = f2bf(q3[i] * sc);
      }
      *(bf16x8*)lb1w = h0; *(bf16x8*)(lb1w + 8) = h1;
    }
    __syncthreads();

    bf16x8 af[4];
    #pragma unroll
    for (int mf = 0; mf < 4; ++mf){
      int row = wm * 64 + mf * 16 + cc;
      af[mf] = *(const bf16x8*)&lA[row * 32 + ((ks ^ ((row >> 1) & 3)) * 8)];
    }
    #pragma unroll
    for (int nf = 0; nf < 4; ++nf){
      int rb = wn * 64 + nf * 16 + cc;
      bf16x8 b0 = *(const bf16x8*)&lB0[rb * 40 + ks * 8];
      bf16x8 b1 = *(const bf16x8*)&lB1[rb * 40 + ks * 8];
      #pragma unroll
      for (int mf = 0; mf < 4; ++mf)
        acc0[mf][nf] = __builtin_amdgcn_mfma_f32_16x16x32_bf16(af[mf], b0, acc0[mf][nf], 0, 0, 0);
      #pragma unroll
      for (int mf = 0; mf < 4; ++mf)
        acc1[mf][nf] = __builtin_amdgcn_mfma_f32_16x16x32_bf16(af[mf], b1, acc1[mf][nf], 0, 0, 0);
    }
    __syncthreads();
  }

  const int rbase = wm * 64 + (lane >> 4) * 4;
  #pragma unroll
  for (int mf = 0; mf < 4; ++mf){
    #pragma unroll
    for (int j = 0; j < 4; ++j){
      int row = rbase + mf * 16 + j;
      if (row < vr){
        short* ar = act + (size_t)(mstart + row) * INTER + blockIdx.y * BM + wn * 64 + cc;
        #pragma unroll
        for (int nf = 0; nf < 4; ++nf){
          float g = acc0[mf][nf][j], u = acc1[mf][nf][j];
          float a = g / (1.f + __expf(-g)) * u;
          ar[nf * 16] = f2bf(a);
        }
      }
    }
  }
}

__global__ __launch_bounds__(256) void k_gemm2(
    const short* __restrict__ act,
    const float* __restrict__ w2, const float* __restrict__ s2,
    const int2* __restrict__ tiles, const int* __restrict__ ntiles,
    const int* __restrict__ pair_tk, float* __restrict__ out)
{
  if ((int)blockIdx.x >= *ntiles) return;
  const int2 td = tiles[blockIdx.x];
  const int mstart = td.x;
  const int e  = td.y >> 16;
  const int vr = td.y & 0xFFFF;
  const int tid = threadIdx.x;
  const int lane = tid & 63;

  __shared__ short lA[BM * 32];
  __shared__ short lB[BM * 40];

  const int r0 = tid >> 2, r1 = 64 + (tid >> 2);
  const int seg = tid & 3;
  int p0 = mstart + r0; if (p0 >= NPAIR) p0 = NPAIR - 1;
  int p1 = mstart + r1; if (p1 >= NPAIR) p1 = NPAIR - 1;
  const short* arow0 = act + (size_t)p0 * INTER + (seg ^ ((r0 >> 1) & 3)) * 8;
  const short* arow1 = act + (size_t)p1 * INTER + (seg ^ ((r1 >> 1) & 3)) * 8;
  const short* ldsA0 = &lA[tid * 8];
  const short* ldsA1 = &lA[2048 + tid * 8];

  const int brow = tid >> 1, half = tid & 1;
  const int gbrow = blockIdx.y * BM + brow;
  const float* w2row = w2 + ((size_t)e * HIDDEN + gbrow) * INTER + half * 16;
  const float* s2row = s2 + ((size_t)e * HIDDEN + gbrow) * 11;
  short* lbw = &lB[brow * 40 + half * 16];

  f32x4 acc[4][4];
  #pragma unroll
  for (int i = 0; i < 4; ++i)
    #pragma unroll
    for (int j = 0; j < 4; ++j) acc[i][j] = (f32x4)0.f;

  const int wm = tid >> 7, wn = (tid >> 6) & 1;
  const int cc = lane & 15, ks = lane >> 4;

  for (int kt = 0; kt < INTER / 32; ++kt){
    gld16(arow0 + kt * 32, ldsA0);
    gld16(arow1 + kt * 32, ldsA1);
    {
      float sc = s2row[kt >> 2];
      const float* g = w2row + kt * 32;
      f32x4 q0 = *(const f32x4*)g,       q1 = *(const f32x4*)(g + 4),
            q2 = *(const f32x4*)(g + 8), q3 = *(const f32x4*)(g + 12);
      bf16x8 h0, h1;
      #pragma unroll
      for (int i = 0; i < 4; ++i){
        h0[i] = f2bf(q0[i] * sc); h0[4 + i] = f2bf(q1[i] * sc);
        h1[i] = f2bf(q2[i] * sc); h1[4 + i] = f2bf(q3[i] * sc);
      }
      *(bf16x8*)lbw = h0; *(bf16x8*)(lbw + 8) = h1;
    }
    __syncthreads();

    bf16x8 af[4];
    #pragma unroll
    for (int mf = 0; mf < 4; ++mf){
      int row = wm * 64 + mf * 16 + cc;
      af[mf] = *(const bf16x8*)&lA[row * 32 + ((ks ^ ((row >> 1) & 3)) * 8)];
    }
    #pragma unroll
    for (int nf = 0; nf < 4; ++nf){
      int rb = wn * 64 + nf * 16 + cc;
      bf16x8 b = *(const bf16x8*)&lB[rb * 40 + ks * 8];
      #pragma unroll
      for (int mf = 0; mf < 4; ++mf)
        acc[mf][nf] = __builtin_amdgcn_mfma_f32_16x16x32_bf16(af[mf], b, acc[mf][nf], 0, 0, 0);
    }
    __syncthreads();
  }

  const int rbase = wm * 64 + (lane >> 4) * 4;
  #pragma unroll
  for (int mf = 0; mf < 4; ++mf){
    #pragma unroll
    for (int j = 0; j < 4; ++j){
      int row = rbase + mf * 16 + j;
      if (row < vr){
        int ptk = pair_tk[mstart + row];
        float* orow = out + ((size_t)(ptk >> 3) * TOPK + (ptk & 7)) * HIDDEN
                      + blockIdx.y * BM + wn * 64 + cc;
        #pragma unroll
        for (int nf = 0; nf < 4; ++nf)
          orow[nf * 16] = acc[mf][nf][j];
      }
    }
  }
}

// ---------------- host ----------------

extern "C" void kernel_launch(void* const* d_in, const int* in_sizes, int n_in,
                              void* d_out, int out_size, void* d_ws, size_t ws_size,
                              hipStream_t stream)
{
  const float* x  = (const float*)d_in[0];
  const int*   sel= (const int*)  d_in[1];
  const float* w0 = (const float*)d_in[2];
  const float* s0 = (const float*)d_in[3];
  const float* w1 = (const float*)d_in[4];
  const float* s1 = (const float*)d_in[5];
  const float* w2 = (const float*)d_in[6];
  const float* s2 = (const float*)d_in[7];
  float* out = (float*)d_out;

  char* ws = (char*)d_ws;
  size_t o = 0;
  auto alloc = [&](size_t n){ size_t r = o; o = (o + n + 255) & ~(size_t)255; return r; };
  int*  cnt     = (int*) (ws + alloc(64));
  int*  cursor  = (int*) (ws + alloc(64));
  int*  offsets = (int*) (ws + alloc(68));
  int*  ntiles  = (int*) (ws + alloc(4));
  int*  ntiles2 = (int*) (ws + alloc(4));
  int2* tiles   = (int2*)(ws + alloc(MAXTILES * 8));
  int2* tiles2  = (int2*)(ws + alloc(MAXT2 * 8));
  int*  pair_tk = (int*) (ws + alloc((size_t)NPAIR * 4));
  short* xb     = (short*)(ws + alloc((size_t)TOKENS * HIDDEN * 2));
  short* act    = (short*)(ws + alloc((size_t)NPAIR * INTER * 2));
  const size_t WSZ = (size_t)NEXP * INTER * HIDDEN * 2;   // 92.27 MB each
  short* w0b    = (short*)(ws + alloc(WSZ));
  short* w1b    = (short*)(ws + alloc(WSZ));
  short* w2b    = (short*)(ws + alloc(WSZ));
  const bool predeq = (ws_size >= o);
  (void)in_sizes; (void)n_in; (void)out_size;

  hipMemsetAsync(ws, 0, 512, stream);   // cnt + cursor

  k_xcast  <<<(TOKENS * HIDDEN) / (256 * 8), 256, 0, stream>>>(x, xb);
  k_count  <<<(NPAIR + 255) / 256, 256, 0, stream>>>(sel, cnt);
  k_scan   <<<1, 64, 0, stream>>>(cnt, offsets, tiles, ntiles, tiles2, ntiles2);
  k_scatter<<<(NPAIR + 255) / 256, 256, 0, stream>>>(sel, offsets, cursor, pair_tk);

  if (predeq){
    // dequant w0+w1 merged; w2 AFTER g1 so it doesn't thrash L3 during g1
    k_deq01<<<2 * NEXP * INTER, 256, 0, stream>>>(w0, s0, w1, s1, w0b, w1b);
    k_g1<<<dim3(MAXT2, NT1), 512, 0, stream>>>(xb, w0b, w1b,
                                               tiles2, ntiles2, pair_tk, act);
    k_deqw2<<<2048, 256, 0, stream>>>(w2, s2, w2b);
    k_g2<<<dim3(MAXT2, NT2W), 512, 0, stream>>>(act, w2b,
                                                tiles2, ntiles2, pair_tk, out);
  } else {
    k_gemm1<<<dim3(MAXTILES, NT1), 256, 0, stream>>>(xb, w0, s0, w1, s1,
                                                     tiles, ntiles, pair_tk, act);
    k_gemm2<<<dim3(MAXTILES, NT2), 256, 0, stream>>>(act, w2, s2,
                                                     tiles, ntiles, pair_tk, out);
  }
}